// Round 1
// baseline (2261.772 us; speedup 1.0000x reference)
//
#include <hip/hip_runtime.h>
#include <math.h>

// Problem constants
#define NVAR 3
#define BB 4
#define CC 256
#define C1 128
#define HEADS 4
#define HC 32
#define HH 64
#define WW 64
#define HW 4096
#define HK 16
#define WK 16
#define NS 256
#define RPE_W 127
#define NP 3
// pairs: p=0 -> (i=1,j=0), p=1 -> (i=2,j=0), p=2 -> (i=2,j=1)

// ---------------------------------------------------------------------------
// 1) copy inputs -> output (result starts as x), zero the 12 flow elements
__global__ __launch_bounds__(256) void copy_init(const float* __restrict__ x0,
                                                 const float* __restrict__ x1,
                                                 const float* __restrict__ x2,
                                                 float* __restrict__ out) {
    const long long per4 = (long long)BB * CC * HW / 4;   // float4 per var
    const long long tot4 = 3LL * per4;
    long long stride = (long long)gridDim.x * blockDim.x;
    for (long long i = (long long)blockIdx.x * blockDim.x + threadIdx.x;
         i < tot4 + 12; i += stride) {
        if (i < tot4) {
            int v = (int)(i / per4);
            long long r = i % per4;
            const float4* s = (v == 0) ? (const float4*)x0
                            : (v == 1) ? (const float4*)x1
                                       : (const float4*)x2;
            ((float4*)out)[i] = s[r];
        } else {
            out[3LL * BB * CC * HW + (i - tot4)] = 0.f;
        }
    }
}

// ---------------------------------------------------------------------------
// 2) q = Wq[p] @ x_{qi(p)}[:, :128] + bq   -> qbuf [p][b][128][4096]
__global__ __launch_bounds__(128) void conv_q(const float* __restrict__ x1,
                                              const float* __restrict__ x2,
                                              const float* __restrict__ Wq,
                                              const float* __restrict__ bq,
                                              float* __restrict__ qbuf) {
    // grid: NP*BB*128 tiles of 32 px
    int blk = blockIdx.x;
    int pb = blk >> 7;            // /128
    int tile = blk & 127;
    int p = pb >> 2, b = pb & 3;
    const float* X = ((p == 0) ? x1 : x2) + (long long)b * CC * HW;
    int m0 = tile * 32;
    __shared__ float xt[128][32];
    for (int idx = threadIdx.x; idx < 128 * 32; idx += 128) {
        int cc = idx >> 5, px = idx & 31;
        xt[cc][px] = X[(long long)cc * HW + m0 + px];
    }
    __syncthreads();
    int c = threadIdx.x;
    const float4* Wrow = (const float4*)(Wq + (p * 128 + c) * 128);
    float acc[32];
#pragma unroll
    for (int i = 0; i < 32; i++) acc[i] = 0.f;
    for (int cp4 = 0; cp4 < 32; cp4++) {
        float4 w = Wrow[cp4];
        int cp = cp4 * 4;
#pragma unroll
        for (int i = 0; i < 32; i++) acc[i] += w.x * xt[cp + 0][i];
#pragma unroll
        for (int i = 0; i < 32; i++) acc[i] += w.y * xt[cp + 1][i];
#pragma unroll
        for (int i = 0; i < 32; i++) acc[i] += w.z * xt[cp + 2][i];
#pragma unroll
        for (int i = 0; i < 32; i++) acc[i] += w.w * xt[cp + 3][i];
    }
    float bias = bq[p * 128 + c];
    float* Y = qbuf + (((long long)pb) * 128 + c) * HW + m0;
#pragma unroll
    for (int i = 0; i < 32; i++) Y[i] = acc[i] + bias;
}

// ---------------------------------------------------------------------------
// 3) offset net: depthwise 4x4 s4 conv -> channel LN -> GELU -> 1x1 to 2 -> pos
//    one block (128 threads) per (p,b,s)
__global__ __launch_bounds__(128) void offset_net(const float* __restrict__ qbuf,
                                                  const float* __restrict__ dw_w,
                                                  const float* __restrict__ dw_b,
                                                  const float* __restrict__ ln_g,
                                                  const float* __restrict__ ln_b,
                                                  const float* __restrict__ pw_w,
                                                  float* __restrict__ posb) {
    int blk = blockIdx.x;               // p*1024 + b*256 + s
    int p = blk >> 10;
    int r = blk & 1023;
    int b = r >> 8;
    int s = r & 255;
    int hk = s >> 4, wk = s & 15;
    int c = threadIdx.x;
    const float* qp = qbuf + (((long long)(p * 4 + b)) * 128 + c) * HW;
    const float* dwp = dw_w + (p * 128 + c) * 16;
    float acc = dw_b[p * 128 + c];
#pragma unroll
    for (int ky = 0; ky < 4; ky++)
#pragma unroll
        for (int kx = 0; kx < 4; kx++)
            acc += qp[(hk * 4 + ky) * WW + (wk * 4 + kx)] * dwp[ky * 4 + kx];

    __shared__ float red[128];
    red[c] = acc;
    __syncthreads();
    for (int st = 64; st > 0; st >>= 1) {
        if (c < st) red[c] += red[c + st];
        __syncthreads();
    }
    float mu = red[0] * (1.f / 128.f);
    __syncthreads();
    float d = acc - mu;
    red[c] = d * d;
    __syncthreads();
    for (int st = 64; st > 0; st >>= 1) {
        if (c < st) red[c] += red[c + st];
        __syncthreads();
    }
    float var = red[0] * (1.f / 128.f);
    __syncthreads();
    float y = d * rsqrtf(var + 1e-5f) * ln_g[p * 128 + c] + ln_b[p * 128 + c];
    float g = 0.5f * y * (1.f + erff(y * 0.70710678118654752f));

    red[c] = pw_w[(p * 2 + 0) * 128 + c] * g;
    __syncthreads();
    for (int st = 64; st > 0; st >>= 1) {
        if (c < st) red[c] += red[c + st];
        __syncthreads();
    }
    float off0 = red[0];
    __syncthreads();
    red[c] = pw_w[(p * 2 + 1) * 128 + c] * g;
    __syncthreads();
    for (int st = 64; st > 0; st >>= 1) {
        if (c < st) red[c] += red[c + st];
        __syncthreads();
    }
    float off1 = red[0];
    if (c == 0) {
        float refy = (hk + 0.5f) * (2.f / 15.f) - 1.f;
        float refx = (wk + 0.5f) * (2.f / 15.f) - 1.f;
        float py = fminf(fmaxf(off0 + refy, -1.f), 1.f);
        float px = fminf(fmaxf(off1 + refx, -1.f), 1.f);
        posb[((p * 4 + b) * 256 + s) * 2 + 0] = py;
        posb[((p * 4 + b) * 256 + s) * 2 + 1] = px;
    }
}

// ---------------------------------------------------------------------------
// 4) bilinear sample kv at pos -> xsb [p][b][128][256]
__global__ __launch_bounds__(128) void sample_xs(const float* __restrict__ x0,
                                                 const float* __restrict__ x1,
                                                 const float* __restrict__ posb,
                                                 float* __restrict__ xsb) {
    int blk = blockIdx.x;
    int p = blk >> 10;
    int r = blk & 1023;
    int b = r >> 8;
    int s = r & 255;
    const float* kv = ((p == 2) ? x1 : x0) + (long long)b * CC * HW;
    float gy = posb[((p * 4 + b) * 256 + s) * 2 + 0];
    float gx = posb[((p * 4 + b) * 256 + s) * 2 + 1];
    float xi = (gx + 1.f) * 31.5f;
    float yi = (gy + 1.f) * 31.5f;
    float xf = floorf(xi), yf = floorf(yi);
    int xI = (int)xf, yI = (int)yf;
    float wx = xi - xf, wy = yi - yf;
    int c = threadIdx.x;
    const float* img = kv + (long long)c * HW;
    float v00 = 0.f, v01 = 0.f, v10 = 0.f, v11 = 0.f;
    bool y0ok = (yI >= 0) && (yI < HH);
    bool y1ok = (yI + 1 >= 0) && (yI + 1 < HH);
    bool x0ok = (xI >= 0) && (xI < WW);
    bool x1ok = (xI + 1 >= 0) && (xI + 1 < WW);
    int yc0 = min(max(yI, 0), HH - 1), yc1 = min(max(yI + 1, 0), HH - 1);
    int xc0 = min(max(xI, 0), WW - 1), xc1 = min(max(xI + 1, 0), WW - 1);
    if (y0ok && x0ok) v00 = img[yc0 * WW + xc0];
    if (y0ok && x1ok) v01 = img[yc0 * WW + xc1];
    if (y1ok && x0ok) v10 = img[yc1 * WW + xc0];
    if (y1ok && x1ok) v11 = img[yc1 * WW + xc1];
    float val = (1.f - wy) * ((1.f - wx) * v00 + wx * v01)
              + wy * ((1.f - wx) * v10 + wx * v11);
    xsb[(((long long)(p * 4 + b)) * 128 + c) * 256 + s] = val;
}

// ---------------------------------------------------------------------------
// 5) k/v = W @ xs + b   (xs layout [p][b][128][256])
__global__ __launch_bounds__(128) void conv_ws(const float* __restrict__ X,
                                               const float* __restrict__ W,
                                               const float* __restrict__ bias,
                                               float* __restrict__ Y) {
    // grid: NP*BB*8 tiles of 32 px
    int blk = blockIdx.x;
    int pb = blk >> 3;
    int tile = blk & 7;
    int p = pb >> 2;
    int m0 = tile * 32;
    const float* Xb = X + (long long)pb * 128 * 256;
    __shared__ float xt[128][32];
    for (int idx = threadIdx.x; idx < 128 * 32; idx += 128) {
        int cc = idx >> 5, px = idx & 31;
        xt[cc][px] = Xb[cc * 256 + m0 + px];
    }
    __syncthreads();
    int c = threadIdx.x;
    const float4* Wrow = (const float4*)(W + (p * 128 + c) * 128);
    float acc[32];
#pragma unroll
    for (int i = 0; i < 32; i++) acc[i] = 0.f;
    for (int cp4 = 0; cp4 < 32; cp4++) {
        float4 w = Wrow[cp4];
        int cp = cp4 * 4;
#pragma unroll
        for (int i = 0; i < 32; i++) acc[i] += w.x * xt[cp + 0][i];
#pragma unroll
        for (int i = 0; i < 32; i++) acc[i] += w.y * xt[cp + 1][i];
#pragma unroll
        for (int i = 0; i < 32; i++) acc[i] += w.z * xt[cp + 2][i];
#pragma unroll
        for (int i = 0; i < 32; i++) acc[i] += w.w * xt[cp + 3][i];
    }
    float bv = bias[p * 128 + c];
    float* Yp = Y + (long long)pb * 128 * 256 + c * 256 + m0;
#pragma unroll
    for (int i = 0; i < 32; i++) Yp[i] = acc[i] + bv;
}

// ---------------------------------------------------------------------------
// 6) attention: one wave per (p,b,h, 4 query pixels)
__global__ __launch_bounds__(256) void attn_kernel(const float* __restrict__ qbuf,
                                                   const float* __restrict__ kbuf,
                                                   const float* __restrict__ vbuf,
                                                   const float* __restrict__ posb,
                                                   const float* __restrict__ rpe,
                                                   float* __restrict__ obuf) {
    int wid = threadIdx.x >> 6;
    int lane = threadIdx.x & 63;
    int gw = blockIdx.x * 4 + wid;       // NP*BB*HEADS*1024 waves
    int mt = gw & 1023;
    int m0 = mt * 4;
    int h = (gw >> 10) & 3;
    int b = (gw >> 12) & 3;
    int p = gw >> 14;
    int pb = p * 4 + b;

    __shared__ float qs[4][32][4];
    __shared__ float pr[4][4][256];

    const float* qrow = qbuf + (((long long)pb) * 128 + h * 32) * HW + m0;
#pragma unroll
    for (int r2 = 0; r2 < 2; r2++) {
        int ii = lane + r2 * 64;        // 0..127
        int hc = ii >> 2, mi = ii & 3;
        qs[wid][hc][mi] = qrow[hc * HW + mi];
    }
    // same-wave LDS write->read: lockstep, no block barrier needed

    const float* kbase = kbuf + (((long long)pb) * 128 + h * 32) * 256;
    const float* vbase = vbuf + (((long long)pb) * 128 + h * 32) * 256;
    const float* pp = posb + ((long long)pb) * 256 * 2;
    const float* tab = rpe + ((long long)(p * 4 + h)) * RPE_W * RPE_W;

    int my = m0 >> 6, mx0 = m0 & 63;
    float gy = my * (2.f / 63.f) - 1.f;

    float logit[4][4];
#pragma unroll
    for (int t = 0; t < 4; t++) {
        int n = lane + t * 64;
        float acc[4] = {0.f, 0.f, 0.f, 0.f};
        for (int hc = 0; hc < 32; hc++) {
            float kv = kbase[hc * 256 + n];
#pragma unroll
            for (int mi = 0; mi < 4; mi++) acc[mi] += qs[wid][hc][mi] * kv;
        }
        float py = pp[n * 2 + 0], px = pp[n * 2 + 1];
        float dispy = (gy - py) * 0.5f;
        float yi = (dispy + 1.f) * 63.f;
        float yf = floorf(yi);
        int yI = (int)yf;
        float wy = yi - yf;
        bool y0ok = (yI >= 0) && (yI < RPE_W);
        bool y1ok = (yI + 1 >= 0) && (yI + 1 < RPE_W);
        int yc0 = min(max(yI, 0), RPE_W - 1), yc1 = min(max(yI + 1, 0), RPE_W - 1);
#pragma unroll
        for (int mi = 0; mi < 4; mi++) {
            float gx = (mx0 + mi) * (2.f / 63.f) - 1.f;
            float dispx = (gx - px) * 0.5f;
            float xi = (dispx + 1.f) * 63.f;
            float xf = floorf(xi);
            int xI = (int)xf;
            float wx = xi - xf;
            bool x0ok = (xI >= 0) && (xI < RPE_W);
            bool x1ok = (xI + 1 >= 0) && (xI + 1 < RPE_W);
            int xc0 = min(max(xI, 0), RPE_W - 1), xc1 = min(max(xI + 1, 0), RPE_W - 1);
            float v00 = (y0ok && x0ok) ? tab[yc0 * RPE_W + xc0] : 0.f;
            float v01 = (y0ok && x1ok) ? tab[yc0 * RPE_W + xc1] : 0.f;
            float v10 = (y1ok && x0ok) ? tab[yc1 * RPE_W + xc0] : 0.f;
            float v11 = (y1ok && x1ok) ? tab[yc1 * RPE_W + xc1] : 0.f;
            float biasv = (1.f - wy) * ((1.f - wx) * v00 + wx * v01)
                        + wy * ((1.f - wx) * v10 + wx * v11);
            logit[t][mi] = acc[mi] * 0.17677669529663687f + biasv;
        }
    }

    // softmax over n (256) per mi
#pragma unroll
    for (int mi = 0; mi < 4; mi++) {
        float mx = fmaxf(fmaxf(logit[0][mi], logit[1][mi]),
                         fmaxf(logit[2][mi], logit[3][mi]));
        for (int off = 32; off > 0; off >>= 1) mx = fmaxf(mx, __shfl_xor(mx, off));
        float e[4], ssum = 0.f;
#pragma unroll
        for (int t = 0; t < 4; t++) {
            e[t] = __expf(logit[t][mi] - mx);
            ssum += e[t];
        }
        for (int off = 32; off > 0; off >>= 1) ssum += __shfl_xor(ssum, off);
        float inv = 1.f / ssum;
#pragma unroll
        for (int t = 0; t < 4; t++) pr[wid][mi][lane + t * 64] = e[t] * inv;
    }
    // same-wave LDS, lockstep -> safe

    int c = lane & 31, half = lane >> 5;
    const float* vrow = vbase + c * 256 + half * 128;
    float accO[4] = {0.f, 0.f, 0.f, 0.f};
    for (int nn = 0; nn < 128; nn++) {
        float vv = vrow[nn];
#pragma unroll
        for (int mi = 0; mi < 4; mi++) accO[mi] += pr[wid][mi][half * 128 + nn] * vv;
    }
#pragma unroll
    for (int mi = 0; mi < 4; mi++) accO[mi] += __shfl_down(accO[mi], 32);
    if (lane < 32) {
        float* orow = obuf + (((long long)pb) * 128 + h * 32 + c) * HW + m0;
#pragma unroll
        for (int mi = 0; mi < 4; mi++) orow[mi] = accO[mi];
    }
}

// ---------------------------------------------------------------------------
// 7) attn_out = Wo @ o + bo, added into d_out channels 128:256 of var qi(p)
__global__ __launch_bounds__(128) void conv_wo(const float* __restrict__ obuf,
                                               const float* __restrict__ Wo,
                                               const float* __restrict__ bo,
                                               float* __restrict__ out, int p) {
    int blk = blockIdx.x;               // BB*128
    int b = blk >> 7;
    int tile = blk & 127;
    int m0 = tile * 32;
    const float* X = obuf + ((long long)(p * 4 + b)) * 128 * HW;
    __shared__ float xt[128][32];
    for (int idx = threadIdx.x; idx < 128 * 32; idx += 128) {
        int cc = idx >> 5, px = idx & 31;
        xt[cc][px] = X[(long long)cc * HW + m0 + px];
    }
    __syncthreads();
    int c = threadIdx.x;
    const float4* Wrow = (const float4*)(Wo + (p * 128 + c) * 128);
    float acc[32];
#pragma unroll
    for (int i = 0; i < 32; i++) acc[i] = 0.f;
    for (int cp4 = 0; cp4 < 32; cp4++) {
        float4 w = Wrow[cp4];
        int cp = cp4 * 4;
#pragma unroll
        for (int i = 0; i < 32; i++) acc[i] += w.x * xt[cp + 0][i];
#pragma unroll
        for (int i = 0; i < 32; i++) acc[i] += w.y * xt[cp + 1][i];
#pragma unroll
        for (int i = 0; i < 32; i++) acc[i] += w.z * xt[cp + 2][i];
#pragma unroll
        for (int i = 0; i < 32; i++) acc[i] += w.w * xt[cp + 3][i];
    }
    int qi = (p == 0) ? 1 : 2;
    float bias = bo[p * 128 + c];
    float* Y = out + (((long long)(qi * 4 + b)) * CC + 128 + c) * HW + m0;
#pragma unroll
    for (int i = 0; i < 32; i++) Y[i] += acc[i] + bias;
}

// ---------------------------------------------------------------------------
extern "C" void kernel_launch(void* const* d_in, const int* in_sizes, int n_in,
                              void* d_out, int out_size, void* d_ws, size_t ws_size,
                              hipStream_t stream) {
    const float* x0 = (const float*)d_in[0];
    const float* x1 = (const float*)d_in[1];
    const float* x2 = (const float*)d_in[2];
    const float* Wq = (const float*)d_in[3];
    const float* bq = (const float*)d_in[4];
    const float* Wk = (const float*)d_in[5];
    const float* bk = (const float*)d_in[6];
    const float* Wv = (const float*)d_in[7];
    const float* bv = (const float*)d_in[8];
    const float* Wo = (const float*)d_in[9];
    const float* bo = (const float*)d_in[10];
    const float* dw_w = (const float*)d_in[11];
    const float* dw_b = (const float*)d_in[12];
    const float* ln_g = (const float*)d_in[13];
    const float* ln_b = (const float*)d_in[14];
    const float* pw_w = (const float*)d_in[15];
    const float* rpe = (const float*)d_in[16];
    float* out = (float*)d_out;

    // workspace layout (floats)
    float* ws = (float*)d_ws;
    float* qbuf = ws;                                  // 3*4*128*4096 = 6291456
    float* obuf = qbuf + 6291456;                      // 6291456
    float* posb = obuf + 6291456;                      // 3*4*256*2   = 6144
    float* xsb  = posb + 6144;                         // 3*4*128*256 = 393216
    float* kb   = xsb + 393216;                        // 393216
    float* vb   = kb + 393216;                         // 393216
    // total ~ 55.1 MB

    copy_init<<<2048, 256, 0, stream>>>(x0, x1, x2, out);
    conv_q<<<NP * BB * 128, 128, 0, stream>>>(x1, x2, Wq, bq, qbuf);
    offset_net<<<NP * BB * 256, 128, 0, stream>>>(qbuf, dw_w, dw_b, ln_g, ln_b,
                                                  pw_w, posb);
    sample_xs<<<NP * BB * 256, 128, 0, stream>>>(x0, x1, posb, xsb);
    conv_ws<<<NP * BB * 8, 128, 0, stream>>>(xsb, Wk, bk, kb);
    conv_ws<<<NP * BB * 8, 128, 0, stream>>>(xsb, Wv, bv, vb);
    attn_kernel<<<NP * BB * HEADS * 256, 256, 0, stream>>>(qbuf, kb, vb, posb,
                                                           rpe, obuf);
    conv_wo<<<BB * 128, 128, 0, stream>>>(obuf, Wo, bo, out, 0);
    conv_wo<<<BB * 128, 128, 0, stream>>>(obuf, Wo, bo, out, 1);
    conv_wo<<<BB * 128, 128, 0, stream>>>(obuf, Wo, bo, out, 2);
}

// Round 2
// 635.540 us; speedup vs baseline: 3.5588x; 3.5588x over previous
//
#include <hip/hip_runtime.h>
#include <math.h>

// Problem constants
#define NVAR 3
#define BB 4
#define CC 256
#define C1 128
#define HEADS 4
#define HC 32
#define HH 64
#define WW 64
#define HW 4096
#define HK 16
#define WK 16
#define NS 256
#define RPE_W 127
#define NP 3
// pairs: p=0 -> (i=1,j=0), p=1 -> (i=2,j=0), p=2 -> (i=2,j=1)

// ---------------------------------------------------------------------------
// 1) copy inputs -> output (result starts as x), zero the 12 flow elements
__global__ __launch_bounds__(256) void copy_init(const float* __restrict__ x0,
                                                 const float* __restrict__ x1,
                                                 const float* __restrict__ x2,
                                                 float* __restrict__ out) {
    const long long per4 = (long long)BB * CC * HW / 4;   // float4 per var
    const long long tot4 = 3LL * per4;
    long long stride = (long long)gridDim.x * blockDim.x;
    for (long long i = (long long)blockIdx.x * blockDim.x + threadIdx.x;
         i < tot4 + 12; i += stride) {
        if (i < tot4) {
            int v = (int)(i / per4);
            long long r = i % per4;
            const float4* s = (v == 0) ? (const float4*)x0
                            : (v == 1) ? (const float4*)x1
                                       : (const float4*)x2;
            ((float4*)out)[i] = s[r];
        } else {
            out[3LL * BB * CC * HW + (i - tot4)] = 0.f;
        }
    }
}

// ---------------------------------------------------------------------------
// 2) q = Wq[p] @ x_{qi(p)}[:, :128] + bq   -> qbuf [p][b][128][4096]
__global__ __launch_bounds__(128) void conv_q(const float* __restrict__ x1,
                                              const float* __restrict__ x2,
                                              const float* __restrict__ Wq,
                                              const float* __restrict__ bq,
                                              float* __restrict__ qbuf) {
    // grid: NP*BB*128 tiles of 32 px
    int blk = blockIdx.x;
    int pb = blk >> 7;            // /128
    int tile = blk & 127;
    int p = pb >> 2, b = pb & 3;
    const float* X = ((p == 0) ? x1 : x2) + (long long)b * CC * HW;
    int m0 = tile * 32;
    __shared__ float xt[128][32];
    for (int idx = threadIdx.x; idx < 128 * 32; idx += 128) {
        int cc = idx >> 5, px = idx & 31;
        xt[cc][px] = X[(long long)cc * HW + m0 + px];
    }
    __syncthreads();
    int c = threadIdx.x;
    const float4* Wrow = (const float4*)(Wq + (p * 128 + c) * 128);
    float acc[32];
#pragma unroll
    for (int i = 0; i < 32; i++) acc[i] = 0.f;
    for (int cp4 = 0; cp4 < 32; cp4++) {
        float4 w = Wrow[cp4];
        int cp = cp4 * 4;
#pragma unroll
        for (int i = 0; i < 32; i++) acc[i] += w.x * xt[cp + 0][i];
#pragma unroll
        for (int i = 0; i < 32; i++) acc[i] += w.y * xt[cp + 1][i];
#pragma unroll
        for (int i = 0; i < 32; i++) acc[i] += w.z * xt[cp + 2][i];
#pragma unroll
        for (int i = 0; i < 32; i++) acc[i] += w.w * xt[cp + 3][i];
    }
    float bias = bq[p * 128 + c];
    float* Y = qbuf + (((long long)pb) * 128 + c) * HW + m0;
#pragma unroll
    for (int i = 0; i < 32; i++) Y[i] = acc[i] + bias;
}

// ---------------------------------------------------------------------------
// 3) offset net: depthwise 4x4 s4 conv -> channel LN -> GELU -> 1x1 to 2 -> pos
//    one block (128 threads) per (p,b,s)
__global__ __launch_bounds__(128) void offset_net(const float* __restrict__ qbuf,
                                                  const float* __restrict__ dw_w,
                                                  const float* __restrict__ dw_b,
                                                  const float* __restrict__ ln_g,
                                                  const float* __restrict__ ln_b,
                                                  const float* __restrict__ pw_w,
                                                  float* __restrict__ posb) {
    int blk = blockIdx.x;               // p*1024 + b*256 + s
    int p = blk >> 10;
    int r = blk & 1023;
    int b = r >> 8;
    int s = r & 255;
    int hk = s >> 4, wk = s & 15;
    int c = threadIdx.x;
    const float* qp = qbuf + (((long long)(p * 4 + b)) * 128 + c) * HW;
    const float* dwp = dw_w + (p * 128 + c) * 16;
    float acc = dw_b[p * 128 + c];
#pragma unroll
    for (int ky = 0; ky < 4; ky++)
#pragma unroll
        for (int kx = 0; kx < 4; kx++)
            acc += qp[(hk * 4 + ky) * WW + (wk * 4 + kx)] * dwp[ky * 4 + kx];

    __shared__ float red[128];
    red[c] = acc;
    __syncthreads();
    for (int st = 64; st > 0; st >>= 1) {
        if (c < st) red[c] += red[c + st];
        __syncthreads();
    }
    float mu = red[0] * (1.f / 128.f);
    __syncthreads();
    float d = acc - mu;
    red[c] = d * d;
    __syncthreads();
    for (int st = 64; st > 0; st >>= 1) {
        if (c < st) red[c] += red[c + st];
        __syncthreads();
    }
    float var = red[0] * (1.f / 128.f);
    __syncthreads();
    float y = d * rsqrtf(var + 1e-5f) * ln_g[p * 128 + c] + ln_b[p * 128 + c];
    float g = 0.5f * y * (1.f + erff(y * 0.70710678118654752f));

    red[c] = pw_w[(p * 2 + 0) * 128 + c] * g;
    __syncthreads();
    for (int st = 64; st > 0; st >>= 1) {
        if (c < st) red[c] += red[c + st];
        __syncthreads();
    }
    float off0 = red[0];
    __syncthreads();
    red[c] = pw_w[(p * 2 + 1) * 128 + c] * g;
    __syncthreads();
    for (int st = 64; st > 0; st >>= 1) {
        if (c < st) red[c] += red[c + st];
        __syncthreads();
    }
    float off1 = red[0];
    if (c == 0) {
        float refy = (hk + 0.5f) * (2.f / 15.f) - 1.f;
        float refx = (wk + 0.5f) * (2.f / 15.f) - 1.f;
        float py = fminf(fmaxf(off0 + refy, -1.f), 1.f);
        float px = fminf(fmaxf(off1 + refx, -1.f), 1.f);
        posb[((p * 4 + b) * 256 + s) * 2 + 0] = py;
        posb[((p * 4 + b) * 256 + s) * 2 + 1] = px;
    }
}

// ---------------------------------------------------------------------------
// 4) bilinear sample kv at pos -> xsb [p][b][128][256]
__global__ __launch_bounds__(128) void sample_xs(const float* __restrict__ x0,
                                                 const float* __restrict__ x1,
                                                 const float* __restrict__ posb,
                                                 float* __restrict__ xsb) {
    int blk = blockIdx.x;
    int p = blk >> 10;
    int r = blk & 1023;
    int b = r >> 8;
    int s = r & 255;
    const float* kv = ((p == 2) ? x1 : x0) + (long long)b * CC * HW;
    float gy = posb[((p * 4 + b) * 256 + s) * 2 + 0];
    float gx = posb[((p * 4 + b) * 256 + s) * 2 + 1];
    float xi = (gx + 1.f) * 31.5f;
    float yi = (gy + 1.f) * 31.5f;
    float xf = floorf(xi), yf = floorf(yi);
    int xI = (int)xf, yI = (int)yf;
    float wx = xi - xf, wy = yi - yf;
    int c = threadIdx.x;
    const float* img = kv + (long long)c * HW;
    float v00 = 0.f, v01 = 0.f, v10 = 0.f, v11 = 0.f;
    bool y0ok = (yI >= 0) && (yI < HH);
    bool y1ok = (yI + 1 >= 0) && (yI + 1 < HH);
    bool x0ok = (xI >= 0) && (xI < WW);
    bool x1ok = (xI + 1 >= 0) && (xI + 1 < WW);
    int yc0 = min(max(yI, 0), HH - 1), yc1 = min(max(yI + 1, 0), HH - 1);
    int xc0 = min(max(xI, 0), WW - 1), xc1 = min(max(xI + 1, 0), WW - 1);
    if (y0ok && x0ok) v00 = img[yc0 * WW + xc0];
    if (y0ok && x1ok) v01 = img[yc0 * WW + xc1];
    if (y1ok && x0ok) v10 = img[yc1 * WW + xc0];
    if (y1ok && x1ok) v11 = img[yc1 * WW + xc1];
    float val = (1.f - wy) * ((1.f - wx) * v00 + wx * v01)
              + wy * ((1.f - wx) * v10 + wx * v11);
    xsb[(((long long)(p * 4 + b)) * 128 + c) * 256 + s] = val;
}

// ---------------------------------------------------------------------------
// 5) k/v = W @ xs + b, stored TRANSPOSED: Y [pb][n=256][c=128]
__global__ __launch_bounds__(128) void conv_ws(const float* __restrict__ X,
                                               const float* __restrict__ W,
                                               const float* __restrict__ bias,
                                               float* __restrict__ Y) {
    // grid: NP*BB*8 tiles of 32 px
    int blk = blockIdx.x;
    int pb = blk >> 3;
    int tile = blk & 7;
    int p = pb >> 2;
    int m0 = tile * 32;
    const float* Xb = X + (long long)pb * 128 * 256;
    __shared__ float xt[128][32];
    for (int idx = threadIdx.x; idx < 128 * 32; idx += 128) {
        int cc = idx >> 5, px = idx & 31;
        xt[cc][px] = Xb[cc * 256 + m0 + px];
    }
    __syncthreads();
    int c = threadIdx.x;
    const float4* Wrow = (const float4*)(W + (p * 128 + c) * 128);
    float acc[32];
#pragma unroll
    for (int i = 0; i < 32; i++) acc[i] = 0.f;
    for (int cp4 = 0; cp4 < 32; cp4++) {
        float4 w = Wrow[cp4];
        int cp = cp4 * 4;
#pragma unroll
        for (int i = 0; i < 32; i++) acc[i] += w.x * xt[cp + 0][i];
#pragma unroll
        for (int i = 0; i < 32; i++) acc[i] += w.y * xt[cp + 1][i];
#pragma unroll
        for (int i = 0; i < 32; i++) acc[i] += w.z * xt[cp + 2][i];
#pragma unroll
        for (int i = 0; i < 32; i++) acc[i] += w.w * xt[cp + 3][i];
    }
    float bv = bias[p * 128 + c];
    float* Yp = Y + (long long)pb * 256 * 128 + c;
#pragma unroll
    for (int i = 0; i < 32; i++) Yp[(m0 + i) * 128] = acc[i] + bv;  // coalesced per i
}

// ---------------------------------------------------------------------------
// 6) attention: one wave per (p,b,h, query row my). lane = mx.
//    Online softmax over n; q and O live in registers; no LDS; no spill.
__global__ __launch_bounds__(256) void attn_kernel(const float* __restrict__ qbuf,
                                                   const float* __restrict__ kt,
                                                   const float* __restrict__ vt,
                                                   const float* __restrict__ posb,
                                                   const float* __restrict__ rpe,
                                                   float* __restrict__ obuf) {
    int wid = threadIdx.x >> 6;
    int lane = threadIdx.x & 63;
    int gw = blockIdx.x * 4 + wid;      // 3*4*4*64 = 3072 waves
    int my = gw & 63;
    int h = (gw >> 6) & 3;
    int b = (gw >> 8) & 3;
    int p = gw >> 10;
    int pb = p * 4 + b;
    int mx = lane;

    const float* qrow = qbuf + (((long long)pb) * 128 + h * 32) * HW + my * 64 + mx;
    float q[32];
#pragma unroll
    for (int hc = 0; hc < 32; hc++) q[hc] = qrow[hc * HW];

    const float* kbase = kt + ((long long)pb) * 256 * 128 + h * 32;
    const float* vbase = vt + ((long long)pb) * 256 * 128 + h * 32;
    const float* pp = posb + ((long long)pb) * 512;
    const float* tab = rpe + ((long long)(p * 4 + h)) * RPE_W * RPE_W;

    float O[32];
#pragma unroll
    for (int hc = 0; hc < 32; hc++) O[hc] = 0.f;
    float m_run = -1e30f, l_run = 0.f;
    const float fmy = (float)my;

    for (int n = 0; n < 256; n++) {
        const float* kc = kbase + n * 128;
        const float* vc = vbase + n * 128;
        float acc = 0.f;
#pragma unroll
        for (int hc = 0; hc < 32; hc++) acc += q[hc] * kc[hc];

        // RPE bias: x_img = mx + 31.5*(1-px); y_img = my + 31.5*(1-py)
        // weights are uniform per n; gathers are coalesced along mx.
        float py = pp[2 * n + 0], px = pp[2 * n + 1];
        float yimg = fmy + 31.5f * (1.f - py);
        float cx = 31.5f * (1.f - px);
        float yf = floorf(yimg);
        int y0 = (int)yf;
        float wy = yimg - yf;
        int y1 = min(y0 + 1, RPE_W - 1);            // clamped corner has weight 0
        float xf = floorf(cx);
        int xi0 = (int)xf;
        float wx = cx - xf;
        const float* T0 = tab + y0 * RPE_W;
        const float* T1 = tab + y1 * RPE_W;
        int xa = xi0 + mx;                           // <= 126 guaranteed
        int xb = min(xa + 1, RPE_W - 1);             // clamped corner has weight 0
        float a0 = T0[xa], a1 = T0[xb], b0 = T1[xa], b1 = T1[xb];
        float biasv = (1.f - wy) * ((1.f - wx) * a0 + wx * a1)
                    + wy * ((1.f - wx) * b0 + wx * b1);
        float logit = acc * 0.17677669529663687f + biasv;

        // online softmax with defer-max threshold 8
        float d = logit - m_run;
        float pval;
        if (d > 8.f) {
            float s = __expf(-d);
            l_run *= s;
#pragma unroll
            for (int hc = 0; hc < 32; hc++) O[hc] *= s;
            m_run = logit;
            pval = 1.f;
        } else {
            pval = __expf(d);                        // <= e^8, f32-safe
        }
        l_run += pval;
#pragma unroll
        for (int hc = 0; hc < 32; hc++) O[hc] += pval * vc[hc];
    }

    float inv = 1.f / l_run;
    float* orow = obuf + (((long long)pb) * 128 + h * 32) * HW + my * 64 + mx;
#pragma unroll
    for (int hc = 0; hc < 32; hc++) orow[hc * HW] = O[hc] * inv;
}

// ---------------------------------------------------------------------------
// 7) attn_out = Wo @ o + bo, added into d_out channels 128:256 of var qi(p)
__global__ __launch_bounds__(128) void conv_wo(const float* __restrict__ obuf,
                                               const float* __restrict__ Wo,
                                               const float* __restrict__ bo,
                                               float* __restrict__ out, int p) {
    int blk = blockIdx.x;               // BB*128
    int b = blk >> 7;
    int tile = blk & 127;
    int m0 = tile * 32;
    const float* X = obuf + ((long long)(p * 4 + b)) * 128 * HW;
    __shared__ float xt[128][32];
    for (int idx = threadIdx.x; idx < 128 * 32; idx += 128) {
        int cc = idx >> 5, px = idx & 31;
        xt[cc][px] = X[(long long)cc * HW + m0 + px];
    }
    __syncthreads();
    int c = threadIdx.x;
    const float4* Wrow = (const float4*)(Wo + (p * 128 + c) * 128);
    float acc[32];
#pragma unroll
    for (int i = 0; i < 32; i++) acc[i] = 0.f;
    for (int cp4 = 0; cp4 < 32; cp4++) {
        float4 w = Wrow[cp4];
        int cp = cp4 * 4;
#pragma unroll
        for (int i = 0; i < 32; i++) acc[i] += w.x * xt[cp + 0][i];
#pragma unroll
        for (int i = 0; i < 32; i++) acc[i] += w.y * xt[cp + 1][i];
#pragma unroll
        for (int i = 0; i < 32; i++) acc[i] += w.z * xt[cp + 2][i];
#pragma unroll
        for (int i = 0; i < 32; i++) acc[i] += w.w * xt[cp + 3][i];
    }
    int qi = (p == 0) ? 1 : 2;
    float bias = bo[p * 128 + c];
    float* Y = out + (((long long)(qi * 4 + b)) * CC + 128 + c) * HW + m0;
#pragma unroll
    for (int i = 0; i < 32; i++) Y[i] += acc[i] + bias;
}

// ---------------------------------------------------------------------------
extern "C" void kernel_launch(void* const* d_in, const int* in_sizes, int n_in,
                              void* d_out, int out_size, void* d_ws, size_t ws_size,
                              hipStream_t stream) {
    const float* x0 = (const float*)d_in[0];
    const float* x1 = (const float*)d_in[1];
    const float* x2 = (const float*)d_in[2];
    const float* Wq = (const float*)d_in[3];
    const float* bq = (const float*)d_in[4];
    const float* Wk = (const float*)d_in[5];
    const float* bk = (const float*)d_in[6];
    const float* Wv = (const float*)d_in[7];
    const float* bv = (const float*)d_in[8];
    const float* Wo = (const float*)d_in[9];
    const float* bo = (const float*)d_in[10];
    const float* dw_w = (const float*)d_in[11];
    const float* dw_b = (const float*)d_in[12];
    const float* ln_g = (const float*)d_in[13];
    const float* ln_b = (const float*)d_in[14];
    const float* pw_w = (const float*)d_in[15];
    const float* rpe = (const float*)d_in[16];
    float* out = (float*)d_out;

    // workspace layout (floats)
    float* ws = (float*)d_ws;
    float* qbuf = ws;                                  // 3*4*128*4096 = 6291456
    float* obuf = qbuf + 6291456;                      // 6291456
    float* posb = obuf + 6291456;                      // 3*4*256*2   = 6144
    float* xsb  = posb + 6144;                         // 3*4*128*256 = 393216
    float* kt   = xsb + 393216;                        // 393216 (transposed [pb][n][c])
    float* vt   = kt + 393216;                         // 393216
    // total ~ 55.1 MB

    copy_init<<<2048, 256, 0, stream>>>(x0, x1, x2, out);
    conv_q<<<NP * BB * 128, 128, 0, stream>>>(x1, x2, Wq, bq, qbuf);
    offset_net<<<NP * BB * 256, 128, 0, stream>>>(qbuf, dw_w, dw_b, ln_g, ln_b,
                                                  pw_w, posb);
    sample_xs<<<NP * BB * 256, 128, 0, stream>>>(x0, x1, posb, xsb);
    conv_ws<<<NP * BB * 8, 128, 0, stream>>>(xsb, Wk, bk, kt);
    conv_ws<<<NP * BB * 8, 128, 0, stream>>>(xsb, Wv, bv, vt);
    attn_kernel<<<NP * BB * HEADS * 64 / 4, 256, 0, stream>>>(qbuf, kt, vt, posb,
                                                              rpe, obuf);
    conv_wo<<<BB * 128, 128, 0, stream>>>(obuf, Wo, bo, out, 0);
    conv_wo<<<BB * 128, 128, 0, stream>>>(obuf, Wo, bo, out, 1);
    conv_wo<<<BB * 128, 128, 0, stream>>>(obuf, Wo, bo, out, 2);
}

// Round 3
// 562.329 us; speedup vs baseline: 4.0222x; 1.1302x over previous
//
#include <hip/hip_runtime.h>
#include <math.h>

// Problem constants
#define NVAR 3
#define BB 4
#define CC 256
#define C1 128
#define HEADS 4
#define HC 32
#define HH 64
#define WW 64
#define HW 4096
#define HK 16
#define WK 16
#define NS 256
#define RPE_W 127
#define NP 3
// pairs: p=0 -> (i=1,j=0), p=1 -> (i=2,j=0), p=2 -> (i=2,j=1)

// ---------------------------------------------------------------------------
// 1) copy inputs -> output (result starts as x), zero the 12 flow elements
__global__ __launch_bounds__(256) void copy_init(const float* __restrict__ x0,
                                                 const float* __restrict__ x1,
                                                 const float* __restrict__ x2,
                                                 float* __restrict__ out) {
    const long long per4 = (long long)BB * CC * HW / 4;   // float4 per var
    const long long tot4 = 3LL * per4;
    long long stride = (long long)gridDim.x * blockDim.x;
    for (long long i = (long long)blockIdx.x * blockDim.x + threadIdx.x;
         i < tot4 + 12; i += stride) {
        if (i < tot4) {
            int v = (int)(i / per4);
            long long r = i % per4;
            const float4* s = (v == 0) ? (const float4*)x0
                            : (v == 1) ? (const float4*)x1
                                       : (const float4*)x2;
            ((float4*)out)[i] = s[r];
        } else {
            out[3LL * BB * CC * HW + (i - tot4)] = 0.f;
        }
    }
}

// ---------------------------------------------------------------------------
// 2) q = Wq[p] @ x_{qi(p)}[:, :128] + bq   -> qbuf [p][b][128][4096]
__global__ __launch_bounds__(128) void conv_q(const float* __restrict__ x1,
                                              const float* __restrict__ x2,
                                              const float* __restrict__ Wq,
                                              const float* __restrict__ bq,
                                              float* __restrict__ qbuf) {
    // grid: NP*BB*128 tiles of 32 px
    int blk = blockIdx.x;
    int pb = blk >> 7;            // /128
    int tile = blk & 127;
    int p = pb >> 2, b = pb & 3;
    const float* X = ((p == 0) ? x1 : x2) + (long long)b * CC * HW;
    int m0 = tile * 32;
    __shared__ float xt[128][32];
    for (int idx = threadIdx.x; idx < 128 * 32; idx += 128) {
        int cc = idx >> 5, px = idx & 31;
        xt[cc][px] = X[(long long)cc * HW + m0 + px];
    }
    __syncthreads();
    int c = threadIdx.x;
    const float4* Wrow = (const float4*)(Wq + (p * 128 + c) * 128);
    float acc[32];
#pragma unroll
    for (int i = 0; i < 32; i++) acc[i] = 0.f;
    for (int cp4 = 0; cp4 < 32; cp4++) {
        float4 w = Wrow[cp4];
        int cp = cp4 * 4;
#pragma unroll
        for (int i = 0; i < 32; i++) acc[i] += w.x * xt[cp + 0][i];
#pragma unroll
        for (int i = 0; i < 32; i++) acc[i] += w.y * xt[cp + 1][i];
#pragma unroll
        for (int i = 0; i < 32; i++) acc[i] += w.z * xt[cp + 2][i];
#pragma unroll
        for (int i = 0; i < 32; i++) acc[i] += w.w * xt[cp + 3][i];
    }
    float bias = bq[p * 128 + c];
    float* Y = qbuf + (((long long)pb) * 128 + c) * HW + m0;
#pragma unroll
    for (int i = 0; i < 32; i++) Y[i] = acc[i] + bias;
}

// ---------------------------------------------------------------------------
// 3) offset net: depthwise 4x4 s4 conv -> channel LN -> GELU -> 1x1 to 2 -> pos
__global__ __launch_bounds__(128) void offset_net(const float* __restrict__ qbuf,
                                                  const float* __restrict__ dw_w,
                                                  const float* __restrict__ dw_b,
                                                  const float* __restrict__ ln_g,
                                                  const float* __restrict__ ln_b,
                                                  const float* __restrict__ pw_w,
                                                  float* __restrict__ posb) {
    int blk = blockIdx.x;               // p*1024 + b*256 + s
    int p = blk >> 10;
    int r = blk & 1023;
    int b = r >> 8;
    int s = r & 255;
    int hk = s >> 4, wk = s & 15;
    int c = threadIdx.x;
    const float* qp = qbuf + (((long long)(p * 4 + b)) * 128 + c) * HW;
    const float* dwp = dw_w + (p * 128 + c) * 16;
    float acc = dw_b[p * 128 + c];
#pragma unroll
    for (int ky = 0; ky < 4; ky++)
#pragma unroll
        for (int kx = 0; kx < 4; kx++)
            acc += qp[(hk * 4 + ky) * WW + (wk * 4 + kx)] * dwp[ky * 4 + kx];

    __shared__ float red[128];
    red[c] = acc;
    __syncthreads();
    for (int st = 64; st > 0; st >>= 1) {
        if (c < st) red[c] += red[c + st];
        __syncthreads();
    }
    float mu = red[0] * (1.f / 128.f);
    __syncthreads();
    float d = acc - mu;
    red[c] = d * d;
    __syncthreads();
    for (int st = 64; st > 0; st >>= 1) {
        if (c < st) red[c] += red[c + st];
        __syncthreads();
    }
    float var = red[0] * (1.f / 128.f);
    __syncthreads();
    float y = d * rsqrtf(var + 1e-5f) * ln_g[p * 128 + c] + ln_b[p * 128 + c];
    float g = 0.5f * y * (1.f + erff(y * 0.70710678118654752f));

    red[c] = pw_w[(p * 2 + 0) * 128 + c] * g;
    __syncthreads();
    for (int st = 64; st > 0; st >>= 1) {
        if (c < st) red[c] += red[c + st];
        __syncthreads();
    }
    float off0 = red[0];
    __syncthreads();
    red[c] = pw_w[(p * 2 + 1) * 128 + c] * g;
    __syncthreads();
    for (int st = 64; st > 0; st >>= 1) {
        if (c < st) red[c] += red[c + st];
        __syncthreads();
    }
    float off1 = red[0];
    if (c == 0) {
        float refy = (hk + 0.5f) * (2.f / 15.f) - 1.f;
        float refx = (wk + 0.5f) * (2.f / 15.f) - 1.f;
        float py = fminf(fmaxf(off0 + refy, -1.f), 1.f);
        float px = fminf(fmaxf(off1 + refx, -1.f), 1.f);
        posb[((p * 4 + b) * 256 + s) * 2 + 0] = py;
        posb[((p * 4 + b) * 256 + s) * 2 + 1] = px;
    }
}

// ---------------------------------------------------------------------------
// 4) bilinear sample kv at pos -> xsb [p][b][128][256]
__global__ __launch_bounds__(128) void sample_xs(const float* __restrict__ x0,
                                                 const float* __restrict__ x1,
                                                 const float* __restrict__ posb,
                                                 float* __restrict__ xsb) {
    int blk = blockIdx.x;
    int p = blk >> 10;
    int r = blk & 1023;
    int b = r >> 8;
    int s = r & 255;
    const float* kv = ((p == 2) ? x1 : x0) + (long long)b * CC * HW;
    float gy = posb[((p * 4 + b) * 256 + s) * 2 + 0];
    float gx = posb[((p * 4 + b) * 256 + s) * 2 + 1];
    float xi = (gx + 1.f) * 31.5f;
    float yi = (gy + 1.f) * 31.5f;
    float xf = floorf(xi), yf = floorf(yi);
    int xI = (int)xf, yI = (int)yf;
    float wx = xi - xf, wy = yi - yf;
    int c = threadIdx.x;
    const float* img = kv + (long long)c * HW;
    float v00 = 0.f, v01 = 0.f, v10 = 0.f, v11 = 0.f;
    bool y0ok = (yI >= 0) && (yI < HH);
    bool y1ok = (yI + 1 >= 0) && (yI + 1 < HH);
    bool x0ok = (xI >= 0) && (xI < WW);
    bool x1ok = (xI + 1 >= 0) && (xI + 1 < WW);
    int yc0 = min(max(yI, 0), HH - 1), yc1 = min(max(yI + 1, 0), HH - 1);
    int xc0 = min(max(xI, 0), WW - 1), xc1 = min(max(xI + 1, 0), WW - 1);
    if (y0ok && x0ok) v00 = img[yc0 * WW + xc0];
    if (y0ok && x1ok) v01 = img[yc0 * WW + xc1];
    if (y1ok && x0ok) v10 = img[yc1 * WW + xc0];
    if (y1ok && x1ok) v11 = img[yc1 * WW + xc1];
    float val = (1.f - wy) * ((1.f - wx) * v00 + wx * v01)
              + wy * ((1.f - wx) * v10 + wx * v11);
    xsb[(((long long)(p * 4 + b)) * 128 + c) * 256 + s] = val;
}

// ---------------------------------------------------------------------------
// 5) k AND v = W @ xs + b in one kernel, stored TRANSPOSED: Y [pb][n=256][c=128]
//    256 threads: lower half -> K, upper half -> V, sharing the LDS tile.
__global__ __launch_bounds__(256) void conv_kv(const float* __restrict__ X,
                                               const float* __restrict__ Wk,
                                               const float* __restrict__ bk,
                                               const float* __restrict__ Wv,
                                               const float* __restrict__ bv,
                                               float* __restrict__ KT,
                                               float* __restrict__ VT) {
    // grid: NP*BB*8 tiles of 32 px
    int blk = blockIdx.x;
    int pb = blk >> 3;
    int tile = blk & 7;
    int p = pb >> 2;
    int m0 = tile * 32;
    const float* Xb = X + (long long)pb * 128 * 256;
    __shared__ float xt[128][32];
    for (int idx = threadIdx.x; idx < 128 * 32; idx += 256) {
        int cc = idx >> 5, px = idx & 31;
        xt[cc][px] = Xb[cc * 256 + m0 + px];
    }
    __syncthreads();
    int c = threadIdx.x & 127;
    bool isv = threadIdx.x >= 128;
    const float* W = isv ? Wv : Wk;
    const float* bias = isv ? bv : bk;
    float* Y = isv ? VT : KT;
    const float4* Wrow = (const float4*)(W + (p * 128 + c) * 128);
    float acc[32];
#pragma unroll
    for (int i = 0; i < 32; i++) acc[i] = 0.f;
    for (int cp4 = 0; cp4 < 32; cp4++) {
        float4 w = Wrow[cp4];
        int cp = cp4 * 4;
#pragma unroll
        for (int i = 0; i < 32; i++) acc[i] += w.x * xt[cp + 0][i];
#pragma unroll
        for (int i = 0; i < 32; i++) acc[i] += w.y * xt[cp + 1][i];
#pragma unroll
        for (int i = 0; i < 32; i++) acc[i] += w.z * xt[cp + 2][i];
#pragma unroll
        for (int i = 0; i < 32; i++) acc[i] += w.w * xt[cp + 3][i];
    }
    float bvv = bias[p * 128 + c];
    float* Yp = Y + (long long)pb * 256 * 128 + c;
#pragma unroll
    for (int i = 0; i < 32; i++) Yp[(m0 + i) * 128] = acc[i] + bvv;
}

// ---------------------------------------------------------------------------
// 6) attention: one wave per (p,b,h, query row my). lane = mx.
//    n-loop chunked by 8: independent dot chains (ILP), batched loads,
//    one amortized defer-max rescale per chunk. q, O in registers; no LDS.
__global__ __launch_bounds__(256) void attn_kernel(const float* __restrict__ qbuf,
                                                   const float* __restrict__ kt,
                                                   const float* __restrict__ vt,
                                                   const float* __restrict__ posb,
                                                   const float* __restrict__ rpe,
                                                   float* __restrict__ obuf) {
    int wid = threadIdx.x >> 6;
    int lane = threadIdx.x & 63;
    int gw = blockIdx.x * 4 + wid;      // 3*4*4*64 = 3072 waves
    int my = gw & 63;
    int h = (gw >> 6) & 3;
    int b = (gw >> 8) & 3;
    int p = gw >> 10;
    int pb = p * 4 + b;
    int mx = lane;

    const float* qrow = qbuf + (((long long)pb) * 128 + h * 32) * HW + my * 64 + mx;
    float4 q4[8];
#pragma unroll
    for (int j = 0; j < 8; j++) {
        q4[j].x = qrow[(j * 4 + 0) * HW];
        q4[j].y = qrow[(j * 4 + 1) * HW];
        q4[j].z = qrow[(j * 4 + 2) * HW];
        q4[j].w = qrow[(j * 4 + 3) * HW];
    }

    const float* kbase = kt + ((long long)pb) * 256 * 128 + h * 32;
    const float* vbase = vt + ((long long)pb) * 256 * 128 + h * 32;
    const float* pp = posb + ((long long)pb) * 512;
    const float* tab = rpe + ((long long)(p * 4 + h)) * RPE_W * RPE_W;

    float4 O4[8];
#pragma unroll
    for (int j = 0; j < 8; j++) O4[j] = make_float4(0.f, 0.f, 0.f, 0.f);
    float m_run = -1e30f, l_run = 0.f;
    const float fmy = (float)my;

    for (int ch = 0; ch < 32; ch++) {
        const int n0 = ch * 8;
        const float* kc = kbase + (long long)n0 * 128;
        const float* vc = vbase + (long long)n0 * 128;

        // ---- QK^T: 8 independent dot chains, loads batched ----
        float acc[8];
#pragma unroll
        for (int t = 0; t < 8; t++) acc[t] = 0.f;
#pragma unroll
        for (int j = 0; j < 8; j++) {
            float4 qv = q4[j];
#pragma unroll
            for (int t = 0; t < 8; t++) {
                float4 kk = *(const float4*)(kc + t * 128 + j * 4);
                acc[t] += qv.x * kk.x + qv.y * kk.y + qv.z * kk.z + qv.w * kk.w;
            }
        }

        // ---- RPE bias + logits ----
        float logit[8];
#pragma unroll
        for (int t = 0; t < 8; t++) {
            float py = pp[2 * (n0 + t) + 0];
            float px = pp[2 * (n0 + t) + 1];
            float yimg = fmy + 31.5f * (1.f - py);
            float cx = 31.5f * (1.f - px);
            float yf = floorf(yimg);
            int y0 = (int)yf;
            float wy = yimg - yf;
            int y1 = min(y0 + 1, RPE_W - 1);        // clamped corner weight 0
            float xf = floorf(cx);
            int xi0 = (int)xf;
            float wx = cx - xf;
            const float* T0 = tab + y0 * RPE_W;
            const float* T1 = tab + y1 * RPE_W;
            int xa = xi0 + mx;                       // <= 126 guaranteed
            int xb2 = min(xa + 1, RPE_W - 1);        // clamped corner weight 0
            float a0 = T0[xa], a1 = T0[xb2], b0 = T1[xa], b1 = T1[xb2];
            float biasv = (1.f - wy) * ((1.f - wx) * a0 + wx * a1)
                        + wy * ((1.f - wx) * b0 + wx * b1);
            logit[t] = acc[t] * 0.17677669529663687f + biasv;
        }

        // ---- one defer-max rescale per chunk ----
        float cmax = logit[0];
#pragma unroll
        for (int t = 1; t < 8; t++) cmax = fmaxf(cmax, logit[t]);
        if (__any(cmax - m_run > 8.f)) {
            float m_new = fmaxf(m_run, cmax);
            float s = __expf(m_run - m_new);
            l_run *= s;
#pragma unroll
            for (int j = 0; j < 8; j++) {
                O4[j].x *= s; O4[j].y *= s; O4[j].z *= s; O4[j].w *= s;
            }
            m_run = m_new;
        }
        float pv[8], lsum = 0.f;
#pragma unroll
        for (int t = 0; t < 8; t++) {
            pv[t] = __expf(logit[t] - m_run);        // <= e^8, f32-safe
            lsum += pv[t];
        }
        l_run += lsum;

        // ---- PV: batched V loads, 8-way ILP ----
#pragma unroll
        for (int j = 0; j < 8; j++) {
            float4 o = O4[j];
#pragma unroll
            for (int t = 0; t < 8; t++) {
                float4 vv = *(const float4*)(vc + t * 128 + j * 4);
                o.x += pv[t] * vv.x;
                o.y += pv[t] * vv.y;
                o.z += pv[t] * vv.z;
                o.w += pv[t] * vv.w;
            }
            O4[j] = o;
        }
    }

    float inv = 1.f / l_run;
    float* orow = obuf + (((long long)pb) * 128 + h * 32) * HW + my * 64 + mx;
#pragma unroll
    for (int j = 0; j < 8; j++) {
        orow[(j * 4 + 0) * HW] = O4[j].x * inv;
        orow[(j * 4 + 1) * HW] = O4[j].y * inv;
        orow[(j * 4 + 2) * HW] = O4[j].z * inv;
        orow[(j * 4 + 3) * HW] = O4[j].w * inv;
    }
}

// ---------------------------------------------------------------------------
// 7) attn_out = Wo @ o + bo, added into d_out channels 128:256.
//    One launch: vs=0 -> var1 (p=0); vs=1 -> var2 (p=1 AND p=2, K=256).
__global__ __launch_bounds__(128) void conv_wo(const float* __restrict__ obuf,
                                               const float* __restrict__ Wo,
                                               const float* __restrict__ bo,
                                               float* __restrict__ out) {
    int blk = blockIdx.x;               // 2*BB*128 = 1024
    int vs = blk >> 9;
    int r = blk & 511;
    int b = r >> 7;
    int tile = r & 127;
    int m0 = tile * 32;
    int np = vs + 1;
    __shared__ float xt[256][32];
    for (int pi = 0; pi < np; pi++) {
        int p = vs ? (1 + pi) : 0;
        const float* X = obuf + ((long long)(p * 4 + b)) * 128 * HW;
        for (int idx = threadIdx.x; idx < 128 * 32; idx += 128) {
            int cc = idx >> 5, px = idx & 31;
            xt[pi * 128 + cc][px] = X[(long long)cc * HW + m0 + px];
        }
    }
    __syncthreads();
    int c = threadIdx.x;
    float acc[32];
#pragma unroll
    for (int i = 0; i < 32; i++) acc[i] = 0.f;
    float bias = 0.f;
    for (int pi = 0; pi < np; pi++) {
        int p = vs ? (1 + pi) : 0;
        bias += bo[p * 128 + c];
        const float4* Wrow = (const float4*)(Wo + (p * 128 + c) * 128);
        for (int cp4 = 0; cp4 < 32; cp4++) {
            float4 w = Wrow[cp4];
            int cp = pi * 128 + cp4 * 4;
#pragma unroll
            for (int i = 0; i < 32; i++) acc[i] += w.x * xt[cp + 0][i];
#pragma unroll
            for (int i = 0; i < 32; i++) acc[i] += w.y * xt[cp + 1][i];
#pragma unroll
            for (int i = 0; i < 32; i++) acc[i] += w.z * xt[cp + 2][i];
#pragma unroll
            for (int i = 0; i < 32; i++) acc[i] += w.w * xt[cp + 3][i];
        }
    }
    int qi = vs + 1;
    float* Y = out + (((long long)(qi * 4 + b)) * CC + 128 + c) * HW + m0;
#pragma unroll
    for (int i = 0; i < 32; i++) Y[i] += acc[i] + bias;
}

// ---------------------------------------------------------------------------
extern "C" void kernel_launch(void* const* d_in, const int* in_sizes, int n_in,
                              void* d_out, int out_size, void* d_ws, size_t ws_size,
                              hipStream_t stream) {
    const float* x0 = (const float*)d_in[0];
    const float* x1 = (const float*)d_in[1];
    const float* x2 = (const float*)d_in[2];
    const float* Wq = (const float*)d_in[3];
    const float* bq = (const float*)d_in[4];
    const float* Wk = (const float*)d_in[5];
    const float* bk = (const float*)d_in[6];
    const float* Wv = (const float*)d_in[7];
    const float* bv = (const float*)d_in[8];
    const float* Wo = (const float*)d_in[9];
    const float* bo = (const float*)d_in[10];
    const float* dw_w = (const float*)d_in[11];
    const float* dw_b = (const float*)d_in[12];
    const float* ln_g = (const float*)d_in[13];
    const float* ln_b = (const float*)d_in[14];
    const float* pw_w = (const float*)d_in[15];
    const float* rpe = (const float*)d_in[16];
    float* out = (float*)d_out;

    // workspace layout (floats)
    float* ws = (float*)d_ws;
    float* qbuf = ws;                                  // 3*4*128*4096 = 6291456
    float* obuf = qbuf + 6291456;                      // 6291456
    float* posb = obuf + 6291456;                      // 3*4*256*2   = 6144
    float* xsb  = posb + 6144;                         // 3*4*128*256 = 393216
    float* kt   = xsb + 393216;                        // 393216 (transposed [pb][n][c])
    float* vt   = kt + 393216;                         // 393216
    // total ~ 55.1 MB

    copy_init<<<2048, 256, 0, stream>>>(x0, x1, x2, out);
    conv_q<<<NP * BB * 128, 128, 0, stream>>>(x1, x2, Wq, bq, qbuf);
    offset_net<<<NP * BB * 256, 128, 0, stream>>>(qbuf, dw_w, dw_b, ln_g, ln_b,
                                                  pw_w, posb);
    sample_xs<<<NP * BB * 256, 128, 0, stream>>>(x0, x1, posb, xsb);
    conv_kv<<<NP * BB * 8, 256, 0, stream>>>(xsb, Wk, bk, Wv, bv, kt, vt);
    attn_kernel<<<NP * BB * HEADS * 64 / 4, 256, 0, stream>>>(qbuf, kt, vt, posb,
                                                              rpe, obuf);
    conv_wo<<<2 * BB * 128, 128, 0, stream>>>(obuf, Wo, bo, out);
}

// Round 4
// 287.172 us; speedup vs baseline: 7.8760x; 1.9582x over previous
//
#include <hip/hip_runtime.h>
#include <math.h>

// Problem constants
#define NVAR 3
#define BB 4
#define CC 256
#define C1 128
#define HEADS 4
#define HC 32
#define HH 64
#define WW 64
#define HW 4096
#define HK 16
#define WK 16
#define NS 256
#define RPE_W 127
#define NP 3
// pairs: p=0 -> (i=1,j=0), p=1 -> (i=2,j=0), p=2 -> (i=2,j=1)

typedef short bf16x8 __attribute__((ext_vector_type(8)));
typedef float f32x4 __attribute__((ext_vector_type(4)));

__device__ __forceinline__ unsigned short f2bf(float f) {
    unsigned int u = __float_as_uint(f);
    u += 0x7fffu + ((u >> 16) & 1u);          // round-to-nearest-even
    return (unsigned short)(u >> 16);
}

// ---------------------------------------------------------------------------
// 1) copy inputs -> output (result starts as x), zero the 12 flow elements
__global__ __launch_bounds__(256) void copy_init(const float* __restrict__ x0,
                                                 const float* __restrict__ x1,
                                                 const float* __restrict__ x2,
                                                 float* __restrict__ out) {
    const long long per4 = (long long)BB * CC * HW / 4;   // float4 per var
    const long long tot4 = 3LL * per4;
    long long stride = (long long)gridDim.x * blockDim.x;
    for (long long i = (long long)blockIdx.x * blockDim.x + threadIdx.x;
         i < tot4 + 12; i += stride) {
        if (i < tot4) {
            int v = (int)(i / per4);
            long long r = i % per4;
            const float4* s = (v == 0) ? (const float4*)x0
                            : (v == 1) ? (const float4*)x1
                                       : (const float4*)x2;
            ((float4*)out)[i] = s[r];
        } else {
            out[3LL * BB * CC * HW + (i - tot4)] = 0.f;
        }
    }
}

// ---------------------------------------------------------------------------
// 2) q = Wq[p] @ x_{qi(p)}[:, :128] + bq
//    outputs: qbuf f32 [pb][c][4096] (for offset net) and qbf bf16 [pb][m][c]
__global__ __launch_bounds__(128) void conv_q(const float* __restrict__ x1,
                                              const float* __restrict__ x2,
                                              const float* __restrict__ Wq,
                                              const float* __restrict__ bq,
                                              float* __restrict__ qbuf,
                                              unsigned short* __restrict__ qbf) {
    // grid: NP*BB*128 tiles of 32 px
    int blk = blockIdx.x;
    int pb = blk >> 7;            // /128
    int tile = blk & 127;
    int p = pb >> 2, b = pb & 3;
    const float* X = ((p == 0) ? x1 : x2) + (long long)b * CC * HW;
    int m0 = tile * 32;
    __shared__ float xt[128][32];
    for (int idx = threadIdx.x; idx < 128 * 32; idx += 128) {
        int cc = idx >> 5, px = idx & 31;
        xt[cc][px] = X[(long long)cc * HW + m0 + px];
    }
    __syncthreads();
    int c = threadIdx.x;
    const float4* Wrow = (const float4*)(Wq + (p * 128 + c) * 128);
    float acc[32];
#pragma unroll
    for (int i = 0; i < 32; i++) acc[i] = 0.f;
    for (int cp4 = 0; cp4 < 32; cp4++) {
        float4 w = Wrow[cp4];
        int cp = cp4 * 4;
#pragma unroll
        for (int i = 0; i < 32; i++) acc[i] += w.x * xt[cp + 0][i];
#pragma unroll
        for (int i = 0; i < 32; i++) acc[i] += w.y * xt[cp + 1][i];
#pragma unroll
        for (int i = 0; i < 32; i++) acc[i] += w.z * xt[cp + 2][i];
#pragma unroll
        for (int i = 0; i < 32; i++) acc[i] += w.w * xt[cp + 3][i];
    }
    float bias = bq[p * 128 + c];
    float* Y = qbuf + (((long long)pb) * 128 + c) * HW + m0;
    unsigned short* Yb = qbf + (((long long)pb) * HW + m0) * 128 + c;
#pragma unroll
    for (int i = 0; i < 32; i++) {
        float v = acc[i] + bias;
        Y[i] = v;
        Yb[i * 128] = f2bf(v);
    }
}

// ---------------------------------------------------------------------------
// 3) offset net: depthwise 4x4 s4 conv -> channel LN -> GELU -> 1x1 to 2 -> pos
__global__ __launch_bounds__(128) void offset_net(const float* __restrict__ qbuf,
                                                  const float* __restrict__ dw_w,
                                                  const float* __restrict__ dw_b,
                                                  const float* __restrict__ ln_g,
                                                  const float* __restrict__ ln_b,
                                                  const float* __restrict__ pw_w,
                                                  float* __restrict__ posb) {
    int blk = blockIdx.x;               // p*1024 + b*256 + s
    int p = blk >> 10;
    int r = blk & 1023;
    int b = r >> 8;
    int s = r & 255;
    int hk = s >> 4, wk = s & 15;
    int c = threadIdx.x;
    const float* qp = qbuf + (((long long)(p * 4 + b)) * 128 + c) * HW;
    const float* dwp = dw_w + (p * 128 + c) * 16;
    float acc = dw_b[p * 128 + c];
#pragma unroll
    for (int ky = 0; ky < 4; ky++)
#pragma unroll
        for (int kx = 0; kx < 4; kx++)
            acc += qp[(hk * 4 + ky) * WW + (wk * 4 + kx)] * dwp[ky * 4 + kx];

    __shared__ float red[128];
    red[c] = acc;
    __syncthreads();
    for (int st = 64; st > 0; st >>= 1) {
        if (c < st) red[c] += red[c + st];
        __syncthreads();
    }
    float mu = red[0] * (1.f / 128.f);
    __syncthreads();
    float d = acc - mu;
    red[c] = d * d;
    __syncthreads();
    for (int st = 64; st > 0; st >>= 1) {
        if (c < st) red[c] += red[c + st];
        __syncthreads();
    }
    float var = red[0] * (1.f / 128.f);
    __syncthreads();
    float y = d * rsqrtf(var + 1e-5f) * ln_g[p * 128 + c] + ln_b[p * 128 + c];
    float g = 0.5f * y * (1.f + erff(y * 0.70710678118654752f));

    red[c] = pw_w[(p * 2 + 0) * 128 + c] * g;
    __syncthreads();
    for (int st = 64; st > 0; st >>= 1) {
        if (c < st) red[c] += red[c + st];
        __syncthreads();
    }
    float off0 = red[0];
    __syncthreads();
    red[c] = pw_w[(p * 2 + 1) * 128 + c] * g;
    __syncthreads();
    for (int st = 64; st > 0; st >>= 1) {
        if (c < st) red[c] += red[c + st];
        __syncthreads();
    }
    float off1 = red[0];
    if (c == 0) {
        float refy = (hk + 0.5f) * (2.f / 15.f) - 1.f;
        float refx = (wk + 0.5f) * (2.f / 15.f) - 1.f;
        float py = fminf(fmaxf(off0 + refy, -1.f), 1.f);
        float px = fminf(fmaxf(off1 + refx, -1.f), 1.f);
        posb[((p * 4 + b) * 256 + s) * 2 + 0] = py;
        posb[((p * 4 + b) * 256 + s) * 2 + 1] = px;
    }
}

// ---------------------------------------------------------------------------
// 4) bilinear sample kv at pos -> xsb [p][b][128][256]
__global__ __launch_bounds__(128) void sample_xs(const float* __restrict__ x0,
                                                 const float* __restrict__ x1,
                                                 const float* __restrict__ posb,
                                                 float* __restrict__ xsb) {
    int blk = blockIdx.x;
    int p = blk >> 10;
    int r = blk & 1023;
    int b = r >> 8;
    int s = r & 255;
    const float* kv = ((p == 2) ? x1 : x0) + (long long)b * CC * HW;
    float gy = posb[((p * 4 + b) * 256 + s) * 2 + 0];
    float gx = posb[((p * 4 + b) * 256 + s) * 2 + 1];
    float xi = (gx + 1.f) * 31.5f;
    float yi = (gy + 1.f) * 31.5f;
    float xf = floorf(xi), yf = floorf(yi);
    int xI = (int)xf, yI = (int)yf;
    float wx = xi - xf, wy = yi - yf;
    int c = threadIdx.x;
    const float* img = kv + (long long)c * HW;
    float v00 = 0.f, v01 = 0.f, v10 = 0.f, v11 = 0.f;
    bool y0ok = (yI >= 0) && (yI < HH);
    bool y1ok = (yI + 1 >= 0) && (yI + 1 < HH);
    bool x0ok = (xI >= 0) && (xI < WW);
    bool x1ok = (xI + 1 >= 0) && (xI + 1 < WW);
    int yc0 = min(max(yI, 0), HH - 1), yc1 = min(max(yI + 1, 0), HH - 1);
    int xc0 = min(max(xI, 0), WW - 1), xc1 = min(max(xI + 1, 0), WW - 1);
    if (y0ok && x0ok) v00 = img[yc0 * WW + xc0];
    if (y0ok && x1ok) v01 = img[yc0 * WW + xc1];
    if (y1ok && x0ok) v10 = img[yc1 * WW + xc0];
    if (y1ok && x1ok) v11 = img[yc1 * WW + xc1];
    float val = (1.f - wy) * ((1.f - wx) * v00 + wx * v01)
              + wy * ((1.f - wx) * v10 + wx * v11);
    xsb[(((long long)(p * 4 + b)) * 128 + c) * 256 + s] = val;
}

// ---------------------------------------------------------------------------
// 5) k AND v = W @ xs + b, bf16 outputs:
//    kbf [pb][n(256)][c(128)]  (c contiguous)
//    vbf [pb][c(128)][n(256)]  (n contiguous)
__global__ __launch_bounds__(256) void conv_kv(const float* __restrict__ X,
                                               const float* __restrict__ Wk,
                                               const float* __restrict__ bk,
                                               const float* __restrict__ Wv,
                                               const float* __restrict__ bv,
                                               unsigned short* __restrict__ kbf,
                                               unsigned short* __restrict__ vbf) {
    // grid: NP*BB*8 tiles of 32 px
    int blk = blockIdx.x;
    int pb = blk >> 3;
    int tile = blk & 7;
    int p = pb >> 2;
    int m0 = tile * 32;
    const float* Xb = X + (long long)pb * 128 * 256;
    __shared__ float xt[128][32];
    for (int idx = threadIdx.x; idx < 128 * 32; idx += 256) {
        int cc = idx >> 5, px = idx & 31;
        xt[cc][px] = Xb[cc * 256 + m0 + px];
    }
    __syncthreads();
    int c = threadIdx.x & 127;
    bool isv = threadIdx.x >= 128;
    const float* W = isv ? Wv : Wk;
    const float* bias = isv ? bv : bk;
    const float4* Wrow = (const float4*)(W + (p * 128 + c) * 128);
    float acc[32];
#pragma unroll
    for (int i = 0; i < 32; i++) acc[i] = 0.f;
    for (int cp4 = 0; cp4 < 32; cp4++) {
        float4 w = Wrow[cp4];
        int cp = cp4 * 4;
#pragma unroll
        for (int i = 0; i < 32; i++) acc[i] += w.x * xt[cp + 0][i];
#pragma unroll
        for (int i = 0; i < 32; i++) acc[i] += w.y * xt[cp + 1][i];
#pragma unroll
        for (int i = 0; i < 32; i++) acc[i] += w.z * xt[cp + 2][i];
#pragma unroll
        for (int i = 0; i < 32; i++) acc[i] += w.w * xt[cp + 3][i];
    }
    float bvv = bias[p * 128 + c];
    if (!isv) {
        unsigned short* Yp = kbf + ((long long)pb * 256 + m0) * 128 + c;
#pragma unroll
        for (int i = 0; i < 32; i++) Yp[i * 128] = f2bf(acc[i] + bvv);
    } else {
        unsigned short* Yp = vbf + ((long long)pb * 128 + c) * 256 + m0;
#pragma unroll
        for (int k = 0; k < 16; k++) {
            unsigned int pk = (unsigned int)f2bf(acc[2 * k] + bvv)
                            | ((unsigned int)f2bf(acc[2 * k + 1] + bvv) << 16);
            *(unsigned int*)(Yp + 2 * k) = pk;
        }
    }
}

// ---------------------------------------------------------------------------
// 6) MFMA attention. One wave per (p,b,h, 16-row m-tile).
//    Swapped QK^T: S^T[n][m] = mfma(K_frag, Q_frag) -> per lane m=lane&15 fixed,
//    n = 16*ni + 4*(lane>>4) + reg. Bias gathers coalesced along m. Softmax
//    in-register + shfl_xor(16,32). P -> bf16 LDS (swizzled), PV via MFMA.
__global__ __launch_bounds__(256) void attn_mfma(const unsigned short* __restrict__ qbf,
                                                 const unsigned short* __restrict__ kbf,
                                                 const unsigned short* __restrict__ vbf,
                                                 const float* __restrict__ posb,
                                                 const float* __restrict__ rpe,
                                                 float* __restrict__ obuf) {
    __shared__ unsigned short plds[4][4096];      // 8KB per wave
    int wid = threadIdx.x >> 6, lane = threadIdx.x & 63;
    int g = lane >> 4, lm = lane & 15;
    int gw = blockIdx.x * 4 + wid;                // 12288 waves
    int mt = gw & 255;
    int h = (gw >> 8) & 3;
    int b = (gw >> 10) & 3;
    int p = gw >> 12;
    int pb = p * 4 + b;
    int m0 = mt * 16;

    // ---- QK^T (swapped): A = K[n][c], B = Q^T[c][m] ----
    bf16x8 qf = *(const bf16x8*)(qbf + (((long long)pb) * HW + m0 + lm) * 128
                                 + h * 32 + 8 * g);
    const unsigned short* kbase = kbf + ((long long)pb * 256 + lm) * 128
                                  + h * 32 + 8 * g;
    f32x4 zero = {0.f, 0.f, 0.f, 0.f};
    f32x4 acc[16];
#pragma unroll
    for (int ni = 0; ni < 16; ni++) {
        bf16x8 kf = *(const bf16x8*)(kbase + ni * 16 * 128);
        acc[ni] = __builtin_amdgcn_mfma_f32_16x16x32_bf16(kf, qf, zero, 0, 0, 0);
    }

    // ---- RPE bias + scale (coalesced gathers: consecutive lm -> consecutive x) ----
    const float* pp = posb + pb * 512;
    const float* tab = rpe + (long long)(p * 4 + h) * (RPE_W * RPE_W);
    float fmy = (float)(mt >> 2);
    int mx = ((mt & 3) << 4) + lm;
    const float scale = 0.17677669529663687f;
#pragma unroll
    for (int ni = 0; ni < 16; ni++) {
#pragma unroll
        for (int r = 0; r < 4; r++) {
            int n = ni * 16 + g * 4 + r;
            float2 ps = *(const float2*)(pp + 2 * n);
            float yimg = fmy + 31.5f * (1.f - ps.x);
            float cx = 31.5f * (1.f - ps.y);
            float yf = floorf(yimg);
            float wy = yimg - yf;
            int y0 = (int)yf;
            int y1 = min(y0 + 1, RPE_W - 1);
            float xf = floorf(cx);
            float wx = cx - xf;
            int xa = (int)xf + mx;
            int xb2 = min(xa + 1, RPE_W - 1);
            const float* T0 = tab + y0 * RPE_W;
            const float* T1 = tab + y1 * RPE_W;
            float a0 = T0[xa], a1 = T0[xb2], b0 = T1[xa], b1 = T1[xb2];
            float biasv = (1.f - wy) * ((1.f - wx) * a0 + wx * a1)
                        + wy * ((1.f - wx) * b0 + wx * b1);
            acc[ni][r] = acc[ni][r] * scale + biasv;
        }
    }

    // ---- softmax over n (cross-lane over the 4 g-groups) ----
    float mxv = -1e30f;
#pragma unroll
    for (int ni = 0; ni < 16; ni++)
#pragma unroll
        for (int r = 0; r < 4; r++) mxv = fmaxf(mxv, acc[ni][r]);
    mxv = fmaxf(mxv, __shfl_xor(mxv, 16));
    mxv = fmaxf(mxv, __shfl_xor(mxv, 32));
    float sum = 0.f;
#pragma unroll
    for (int ni = 0; ni < 16; ni++)
#pragma unroll
        for (int r = 0; r < 4; r++) {
            float e = __expf(acc[ni][r] - mxv);
            acc[ni][r] = e;
            sum += e;
        }
    sum += __shfl_xor(sum, 16);
    sum += __shfl_xor(sum, 32);

    // ---- P -> bf16 LDS, layout [m=lm][n], row stride 512B, XOR swizzle ----
    char* pl = (char*)plds[wid];
    int swz = (lm & 7) << 4;
    int rowb = lm * 512;
#pragma unroll
    for (int ni = 0; ni < 16; ni++)
#pragma unroll
        for (int rp = 0; rp < 2; rp++) {
            int n = ni * 16 + g * 4 + rp * 2;
            unsigned int pk = (unsigned int)f2bf(acc[ni][rp * 2])
                            | ((unsigned int)f2bf(acc[ni][rp * 2 + 1]) << 16);
            *(unsigned int*)(pl + ((rowb + n * 2) ^ swz)) = pk;
        }

    // ---- PV: O^T[c][m] = sum_n V^T[c][n] P^T[n][m] ----
    f32x4 o0 = zero, o1 = zero;
    const unsigned short* vb0 = vbf + ((long long)pb * 128 + h * 32 + lm) * 256 + 8 * g;
    const unsigned short* vb1 = vb0 + 16 * 256;
#pragma unroll
    for (int st = 0; st < 8; st++) {
        int n0 = st * 32 + 8 * g;
        bf16x8 pf = *(bf16x8*)(pl + ((rowb + n0 * 2) ^ swz));
        bf16x8 v0 = *(const bf16x8*)(vb0 + st * 32);
        bf16x8 v1 = *(const bf16x8*)(vb1 + st * 32);
        o0 = __builtin_amdgcn_mfma_f32_16x16x32_bf16(v0, pf, o0, 0, 0, 0);
        o1 = __builtin_amdgcn_mfma_f32_16x16x32_bf16(v1, pf, o1, 0, 0, 0);
    }

    float inv = 1.f / sum;
    float* ob = obuf + (((long long)pb) * 128 + h * 32) * HW + m0 + lm;
#pragma unroll
    for (int r = 0; r < 4; r++) {
        ob[(g * 4 + r) * HW] = o0[r] * inv;
        ob[(16 + g * 4 + r) * HW] = o1[r] * inv;
    }
}

// ---------------------------------------------------------------------------
// 7) attn_out = Wo @ o + bo, added into d_out channels 128:256.
//    One launch: vs=0 -> var1 (p=0); vs=1 -> var2 (p=1 AND p=2, K=256).
__global__ __launch_bounds__(128) void conv_wo(const float* __restrict__ obuf,
                                               const float* __restrict__ Wo,
                                               const float* __restrict__ bo,
                                               float* __restrict__ out) {
    int blk = blockIdx.x;               // 2*BB*128 = 1024
    int vs = blk >> 9;
    int r = blk & 511;
    int b = r >> 7;
    int tile = r & 127;
    int m0 = tile * 32;
    int np = vs + 1;
    __shared__ float xt[256][32];
    for (int pi = 0; pi < np; pi++) {
        int p = vs ? (1 + pi) : 0;
        const float* X = obuf + ((long long)(p * 4 + b)) * 128 * HW;
        for (int idx = threadIdx.x; idx < 128 * 32; idx += 128) {
            int cc = idx >> 5, px = idx & 31;
            xt[pi * 128 + cc][px] = X[(long long)cc * HW + m0 + px];
        }
    }
    __syncthreads();
    int c = threadIdx.x;
    float acc[32];
#pragma unroll
    for (int i = 0; i < 32; i++) acc[i] = 0.f;
    float bias = 0.f;
    for (int pi = 0; pi < np; pi++) {
        int p = vs ? (1 + pi) : 0;
        bias += bo[p * 128 + c];
        const float4* Wrow = (const float4*)(Wo + (p * 128 + c) * 128);
        for (int cp4 = 0; cp4 < 32; cp4++) {
            float4 w = Wrow[cp4];
            int cp = pi * 128 + cp4 * 4;
#pragma unroll
            for (int i = 0; i < 32; i++) acc[i] += w.x * xt[cp + 0][i];
#pragma unroll
            for (int i = 0; i < 32; i++) acc[i] += w.y * xt[cp + 1][i];
#pragma unroll
            for (int i = 0; i < 32; i++) acc[i] += w.z * xt[cp + 2][i];
#pragma unroll
            for (int i = 0; i < 32; i++) acc[i] += w.w * xt[cp + 3][i];
        }
    }
    int qi = vs + 1;
    float* Y = out + (((long long)(qi * 4 + b)) * CC + 128 + c) * HW + m0;
#pragma unroll
    for (int i = 0; i < 32; i++) Y[i] += acc[i] + bias;
}

// ---------------------------------------------------------------------------
extern "C" void kernel_launch(void* const* d_in, const int* in_sizes, int n_in,
                              void* d_out, int out_size, void* d_ws, size_t ws_size,
                              hipStream_t stream) {
    const float* x0 = (const float*)d_in[0];
    const float* x1 = (const float*)d_in[1];
    const float* x2 = (const float*)d_in[2];
    const float* Wq = (const float*)d_in[3];
    const float* bq = (const float*)d_in[4];
    const float* Wk = (const float*)d_in[5];
    const float* bk = (const float*)d_in[6];
    const float* Wv = (const float*)d_in[7];
    const float* bv = (const float*)d_in[8];
    const float* Wo = (const float*)d_in[9];
    const float* bo = (const float*)d_in[10];
    const float* dw_w = (const float*)d_in[11];
    const float* dw_b = (const float*)d_in[12];
    const float* ln_g = (const float*)d_in[13];
    const float* ln_b = (const float*)d_in[14];
    const float* pw_w = (const float*)d_in[15];
    const float* rpe = (const float*)d_in[16];
    float* out = (float*)d_out;

    // workspace layout (float units)
    float* ws = (float*)d_ws;
    float* qbuf = ws;                                  // 6291456 f
    float* obuf = qbuf + 6291456;                      // 6291456 f
    float* posb = obuf + 6291456;                      // 6144 f
    float* xsb  = posb + 6144;                         // 393216 f
    unsigned short* qbf = (unsigned short*)(xsb + 393216);   // 12582912 shorts
    unsigned short* kbf = qbf + 12582912;                    // 393216 shorts
    unsigned short* vbf = kbf + 393216;                      // 393216 shorts
    // total ~ 66 MB

    copy_init<<<2048, 256, 0, stream>>>(x0, x1, x2, out);
    conv_q<<<NP * BB * 128, 128, 0, stream>>>(x1, x2, Wq, bq, qbuf, qbf);
    offset_net<<<NP * BB * 256, 128, 0, stream>>>(qbuf, dw_w, dw_b, ln_g, ln_b,
                                                  pw_w, posb);
    sample_xs<<<NP * BB * 256, 128, 0, stream>>>(x0, x1, posb, xsb);
    conv_kv<<<NP * BB * 8, 256, 0, stream>>>(xsb, Wk, bk, Wv, bv, kbf, vbf);
    attn_mfma<<<NP * BB * HEADS * 256 / 4, 256, 0, stream>>>(qbf, kbf, vbf,
                                                             posb, rpe, obuf);
    conv_wo<<<2 * BB * 128, 128, 0, stream>>>(obuf, Wo, bo, out);
}

// Round 5
// 251.361 us; speedup vs baseline: 8.9981x; 1.1425x over previous
//
#include <hip/hip_runtime.h>
#include <math.h>

// Problem constants
#define NVAR 3
#define BB 4
#define CC 256
#define C1 128
#define HEADS 4
#define HH 64
#define WW 64
#define HW 4096
#define RPE_W 127
#define NP 3
#define SCALE 0.17677669529663687f
// pairs: p=0 -> (i=1,j=0), p=1 -> (i=2,j=0), p=2 -> (i=2,j=1)

typedef short bf16x8 __attribute__((ext_vector_type(8)));
typedef float f32x4 __attribute__((ext_vector_type(4)));

__device__ __forceinline__ unsigned short f2bf(float f) {
    unsigned int u = __float_as_uint(f);
    u += 0x7fffu + ((u >> 16) & 1u);          // round-to-nearest-even
    return (unsigned short)(u >> 16);
}
__device__ __forceinline__ float bflo(unsigned u) { return __uint_as_float(u << 16); }
__device__ __forceinline__ float bfhi(unsigned u) { return __uint_as_float(u & 0xffff0000u); }

// ---------------------------------------------------------------------------
// 1) copy inputs -> output (result starts as x), zero the 12 flow elements
__global__ __launch_bounds__(256) void copy_init(const float* __restrict__ x0,
                                                 const float* __restrict__ x1,
                                                 const float* __restrict__ x2,
                                                 float* __restrict__ out) {
    const long long per4 = (long long)BB * CC * HW / 4;   // float4 per var
    const long long tot4 = 3LL * per4;
    long long stride = (long long)gridDim.x * blockDim.x;
    for (long long i = (long long)blockIdx.x * blockDim.x + threadIdx.x;
         i < tot4 + 12; i += stride) {
        if (i < tot4) {
            int v = (int)(i / per4);
            long long r = i % per4;
            const float4* s = (v == 0) ? (const float4*)x0
                            : (v == 1) ? (const float4*)x1
                                       : (const float4*)x2;
            ((float4*)out)[i] = s[r];
        } else {
            out[3LL * BB * CC * HW + (i - tot4)] = 0.f;
        }
    }
}

// ---------------------------------------------------------------------------
// 1b) RPE table -> bf16 [p*4+h][128][128], row/col 127 zeroed (weight-0 there)
__global__ __launch_bounds__(256) void prep_table(const float* __restrict__ rpe,
                                                  unsigned short* __restrict__ tabbf) {
    int ph = blockIdx.x;                  // 12
    const float* src = rpe + (long long)ph * RPE_W * RPE_W;
    unsigned short* dst = tabbf + (long long)ph * 16384;
    for (int idx = threadIdx.x; idx < 16384; idx += 256) {
        int y = idx >> 7, x = idx & 127;
        float v = (y < RPE_W && x < RPE_W) ? src[y * RPE_W + x] : 0.f;
        dst[idx] = f2bf(v);
    }
}

// ---------------------------------------------------------------------------
// 2) q = Wq[p] @ x_{qi(p)}[:, :128] + bq
//    outputs: qbuf f32 [pb][c][4096] (offset net) and qbf bf16 [pb][m][c] * SCALE
__global__ __launch_bounds__(128) void conv_q(const float* __restrict__ x1,
                                              const float* __restrict__ x2,
                                              const float* __restrict__ Wq,
                                              const float* __restrict__ bq,
                                              float* __restrict__ qbuf,
                                              unsigned short* __restrict__ qbf) {
    int blk = blockIdx.x;
    int pb = blk >> 7;            // /128
    int tile = blk & 127;
    int p = pb >> 2, b = pb & 3;
    const float* X = ((p == 0) ? x1 : x2) + (long long)b * CC * HW;
    int m0 = tile * 32;
    __shared__ float4 xt4[128][8];
    for (int idx = threadIdx.x; idx < 1024; idx += 128) {
        int cc = idx >> 3, i8 = idx & 7;
        xt4[cc][i8] = *(const float4*)(X + (long long)cc * HW + m0 + i8 * 4);
    }
    __syncthreads();
    int c = threadIdx.x;
    const float4* Wrow = (const float4*)(Wq + (p * 128 + c) * 128);
    float4 a4[8];
#pragma unroll
    for (int i = 0; i < 8; i++) a4[i] = make_float4(0.f, 0.f, 0.f, 0.f);
    for (int cp4 = 0; cp4 < 32; cp4++) {
        float4 w = Wrow[cp4];
#pragma unroll
        for (int k = 0; k < 4; k++) {
            float wv = (k == 0) ? w.x : (k == 1) ? w.y : (k == 2) ? w.z : w.w;
#pragma unroll
            for (int i = 0; i < 8; i++) {
                float4 xv = xt4[cp4 * 4 + k][i];
                a4[i].x += wv * xv.x; a4[i].y += wv * xv.y;
                a4[i].z += wv * xv.z; a4[i].w += wv * xv.w;
            }
        }
    }
    float bias = bq[p * 128 + c];
    float* Y = qbuf + (((long long)pb) * 128 + c) * HW + m0;
    unsigned short* Yb = qbf + (((long long)pb) * HW + m0) * 128 + c;
#pragma unroll
    for (int i = 0; i < 8; i++) {
        float4 v = a4[i];
        v.x += bias; v.y += bias; v.z += bias; v.w += bias;
        *(float4*)(Y + i * 4) = v;
        Yb[(i * 4 + 0) * 128] = f2bf(v.x * SCALE);
        Yb[(i * 4 + 1) * 128] = f2bf(v.y * SCALE);
        Yb[(i * 4 + 2) * 128] = f2bf(v.z * SCALE);
        Yb[(i * 4 + 3) * 128] = f2bf(v.w * SCALE);
    }
}

// ---------------------------------------------------------------------------
// 3) offset net: depthwise 4x4 s4 conv -> channel LN -> GELU -> 1x1 to 2 -> pos
__global__ __launch_bounds__(128) void offset_net(const float* __restrict__ qbuf,
                                                  const float* __restrict__ dw_w,
                                                  const float* __restrict__ dw_b,
                                                  const float* __restrict__ ln_g,
                                                  const float* __restrict__ ln_b,
                                                  const float* __restrict__ pw_w,
                                                  float* __restrict__ posb) {
    int blk = blockIdx.x;               // p*1024 + b*256 + s
    int p = blk >> 10;
    int r = blk & 1023;
    int b = r >> 8;
    int s = r & 255;
    int hk = s >> 4, wk = s & 15;
    int c = threadIdx.x;
    const float* qp = qbuf + (((long long)(p * 4 + b)) * 128 + c) * HW;
    const float* dwp = dw_w + (p * 128 + c) * 16;
    float acc = dw_b[p * 128 + c];
#pragma unroll
    for (int ky = 0; ky < 4; ky++)
#pragma unroll
        for (int kx = 0; kx < 4; kx++)
            acc += qp[(hk * 4 + ky) * WW + (wk * 4 + kx)] * dwp[ky * 4 + kx];

    __shared__ float red[128];
    red[c] = acc;
    __syncthreads();
    for (int st = 64; st > 0; st >>= 1) {
        if (c < st) red[c] += red[c + st];
        __syncthreads();
    }
    float mu = red[0] * (1.f / 128.f);
    __syncthreads();
    float d = acc - mu;
    red[c] = d * d;
    __syncthreads();
    for (int st = 64; st > 0; st >>= 1) {
        if (c < st) red[c] += red[c + st];
        __syncthreads();
    }
    float var = red[0] * (1.f / 128.f);
    __syncthreads();
    float y = d * rsqrtf(var + 1e-5f) * ln_g[p * 128 + c] + ln_b[p * 128 + c];
    float g = 0.5f * y * (1.f + erff(y * 0.70710678118654752f));

    red[c] = pw_w[(p * 2 + 0) * 128 + c] * g;
    __syncthreads();
    for (int st = 64; st > 0; st >>= 1) {
        if (c < st) red[c] += red[c + st];
        __syncthreads();
    }
    float off0 = red[0];
    __syncthreads();
    red[c] = pw_w[(p * 2 + 1) * 128 + c] * g;
    __syncthreads();
    for (int st = 64; st > 0; st >>= 1) {
        if (c < st) red[c] += red[c + st];
        __syncthreads();
    }
    float off1 = red[0];
    if (c == 0) {
        float refy = (hk + 0.5f) * (2.f / 15.f) - 1.f;
        float refx = (wk + 0.5f) * (2.f / 15.f) - 1.f;
        float py = fminf(fmaxf(off0 + refy, -1.f), 1.f);
        float px = fminf(fmaxf(off1 + refx, -1.f), 1.f);
        posb[((p * 4 + b) * 256 + s) * 2 + 0] = py;
        posb[((p * 4 + b) * 256 + s) * 2 + 1] = px;
    }
}

// ---------------------------------------------------------------------------
// 3b) per-(pb,n) bias params: {w00|w01, w10|w11 (bf16 pairs), byte offset, 0}
__global__ __launch_bounds__(256) void prep_params(const float* __restrict__ posb,
                                                   uint4* __restrict__ prmb) {
    int pb = blockIdx.x;                  // 12
    int n = threadIdx.x;                  // 256
    float py = posb[(pb * 256 + n) * 2 + 0];
    float px = posb[(pb * 256 + n) * 2 + 1];
    float cy = 31.5f * (1.f - py), cx = 31.5f * (1.f - px);
    float yf = floorf(cy), xf = floorf(cx);
    float wy = cy - yf, wx = cx - xf;
    int Y0 = (int)yf, X0 = (int)xf;
    uint4 v;
    v.x = (unsigned)f2bf((1.f - wy) * (1.f - wx))
        | ((unsigned)f2bf((1.f - wy) * wx) << 16);
    v.y = (unsigned)f2bf(wy * (1.f - wx))
        | ((unsigned)f2bf(wy * wx) << 16);
    v.z = (unsigned)((Y0 * 128 + X0) * 2);
    v.w = 0;
    prmb[pb * 256 + n] = v;
}

// ---------------------------------------------------------------------------
// 4) bilinear sample kv at pos -> xsb [p][b][128][256]
__global__ __launch_bounds__(128) void sample_xs(const float* __restrict__ x0,
                                                 const float* __restrict__ x1,
                                                 const float* __restrict__ posb,
                                                 float* __restrict__ xsb) {
    int blk = blockIdx.x;
    int p = blk >> 10;
    int r = blk & 1023;
    int b = r >> 8;
    int s = r & 255;
    const float* kv = ((p == 2) ? x1 : x0) + (long long)b * CC * HW;
    float gy = posb[((p * 4 + b) * 256 + s) * 2 + 0];
    float gx = posb[((p * 4 + b) * 256 + s) * 2 + 1];
    float xi = (gx + 1.f) * 31.5f;
    float yi = (gy + 1.f) * 31.5f;
    float xf = floorf(xi), yf = floorf(yi);
    int xI = (int)xf, yI = (int)yf;
    float wx = xi - xf, wy = yi - yf;
    int c = threadIdx.x;
    const float* img = kv + (long long)c * HW;
    float v00 = 0.f, v01 = 0.f, v10 = 0.f, v11 = 0.f;
    bool y0ok = (yI >= 0) && (yI < HH);
    bool y1ok = (yI + 1 >= 0) && (yI + 1 < HH);
    bool x0ok = (xI >= 0) && (xI < WW);
    bool x1ok = (xI + 1 >= 0) && (xI + 1 < WW);
    int yc0 = min(max(yI, 0), HH - 1), yc1 = min(max(yI + 1, 0), HH - 1);
    int xc0 = min(max(xI, 0), WW - 1), xc1 = min(max(xI + 1, 0), WW - 1);
    if (y0ok && x0ok) v00 = img[yc0 * WW + xc0];
    if (y0ok && x1ok) v01 = img[yc0 * WW + xc1];
    if (y1ok && x0ok) v10 = img[yc1 * WW + xc0];
    if (y1ok && x1ok) v11 = img[yc1 * WW + xc1];
    float val = (1.f - wy) * ((1.f - wx) * v00 + wx * v01)
              + wy * ((1.f - wx) * v10 + wx * v11);
    xsb[(((long long)(p * 4 + b)) * 128 + c) * 256 + s] = val;
}

// ---------------------------------------------------------------------------
// 5) k AND v = W @ xs + b, bf16 outputs:
//    kbf [pb][n(256)][c(128)]  (c contiguous)
//    vbf [pb][c(128)][n(256)]  (n contiguous)
__global__ __launch_bounds__(256) void conv_kv(const float* __restrict__ X,
                                               const float* __restrict__ Wk,
                                               const float* __restrict__ bk,
                                               const float* __restrict__ Wv,
                                               const float* __restrict__ bv,
                                               unsigned short* __restrict__ kbf,
                                               unsigned short* __restrict__ vbf) {
    int blk = blockIdx.x;                 // NP*BB*8
    int pb = blk >> 3;
    int tile = blk & 7;
    int p = pb >> 2;
    int m0 = tile * 32;
    const float* Xb = X + (long long)pb * 128 * 256;
    __shared__ float4 xt4[128][8];
    for (int idx = threadIdx.x; idx < 1024; idx += 256) {
        int cc = idx >> 3, i8 = idx & 7;
        xt4[cc][i8] = *(const float4*)(Xb + cc * 256 + m0 + i8 * 4);
    }
    __syncthreads();
    int c = threadIdx.x & 127;
    bool isv = threadIdx.x >= 128;
    const float* W = isv ? Wv : Wk;
    const float* bias = isv ? bv : bk;
    const float4* Wrow = (const float4*)(W + (p * 128 + c) * 128);
    float4 a4[8];
#pragma unroll
    for (int i = 0; i < 8; i++) a4[i] = make_float4(0.f, 0.f, 0.f, 0.f);
    for (int cp4 = 0; cp4 < 32; cp4++) {
        float4 w = Wrow[cp4];
#pragma unroll
        for (int k = 0; k < 4; k++) {
            float wv = (k == 0) ? w.x : (k == 1) ? w.y : (k == 2) ? w.z : w.w;
#pragma unroll
            for (int i = 0; i < 8; i++) {
                float4 xv = xt4[cp4 * 4 + k][i];
                a4[i].x += wv * xv.x; a4[i].y += wv * xv.y;
                a4[i].z += wv * xv.z; a4[i].w += wv * xv.w;
            }
        }
    }
    float bvv = bias[p * 128 + c];
    float acc[32];
#pragma unroll
    for (int i = 0; i < 8; i++) {
        acc[i * 4 + 0] = a4[i].x + bvv; acc[i * 4 + 1] = a4[i].y + bvv;
        acc[i * 4 + 2] = a4[i].z + bvv; acc[i * 4 + 3] = a4[i].w + bvv;
    }
    if (!isv) {
        unsigned short* Yp = kbf + ((long long)pb * 256 + m0) * 128 + c;
#pragma unroll
        for (int i = 0; i < 32; i++) Yp[i * 128] = f2bf(acc[i]);
    } else {
        unsigned short* Yp = vbf + ((long long)pb * 128 + c) * 256 + m0;
#pragma unroll
        for (int k = 0; k < 16; k++) {
            unsigned int pk = (unsigned int)f2bf(acc[2 * k])
                            | ((unsigned int)f2bf(acc[2 * k + 1]) << 16);
            *(unsigned int*)(Yp + 2 * k) = pk;
        }
    }
}

// ---------------------------------------------------------------------------
// 6) MFMA attention v2. Block = (p,b,h,my); 4 waves = 4 m-tiles of 16 (mx).
//    RPE table (bf16, 32KB) + per-n params (4KB) staged in LDS; gathers are
//    ds_read_u16 with imm offsets. P exchanged in-register (cvt_pk + shfl).
__global__ __launch_bounds__(256, 4) void attn_mfma(
        const unsigned short* __restrict__ qbf,
        const unsigned short* __restrict__ kbf,
        const unsigned short* __restrict__ vbf,
        const unsigned short* __restrict__ tabbf,
        const uint4* __restrict__ prmb,
        float* __restrict__ obuf) {
    __shared__ unsigned short tab[16384];     // 32 KB
    __shared__ uint4 prm[256];                // 4 KB
    int tid = threadIdx.x;
    int wid = tid >> 6, lane = tid & 63;
    int g = lane >> 4, lm = lane & 15;
    int bid = blockIdx.x;                     // 3072
    int my = bid & 63;
    int h = (bid >> 6) & 3;
    int b = (bid >> 8) & 3;
    int p = bid >> 10;
    int pb = p * 4 + b;

    {   // stage table + params
        const uint4* ts = (const uint4*)(tabbf + (long long)(p * 4 + h) * 16384);
        uint4* td = (uint4*)tab;
#pragma unroll
        for (int i = 0; i < 8; i++) td[tid + i * 256] = ts[tid + i * 256];
        prm[tid] = prmb[pb * 256 + tid];
    }
    __syncthreads();

    int mx = (wid << 4) + lm;

    // ---- QK^T (swapped): A = K[n][c], B = Q^T[c][m]; q pre-scaled ----
    bf16x8 qf = *(const bf16x8*)(qbf + ((long long)pb * HW + my * 64 + mx) * 128
                                 + h * 32 + 8 * g);
    const unsigned short* kbase = kbf + ((long long)pb * 256 + lm) * 128
                                  + h * 32 + 8 * g;
    f32x4 zero = {0.f, 0.f, 0.f, 0.f};
    f32x4 acc[16];
#pragma unroll
    for (int ni = 0; ni < 16; ni++) {
        bf16x8 kf = *(const bf16x8*)(kbase + ni * 16 * 128);
        acc[ni] = __builtin_amdgcn_mfma_f32_16x16x32_bf16(kf, qf, zero, 0, 0, 0);
    }

    // ---- RPE bias from LDS table: 4x ds_read_u16 + 4 FMA per logit ----
    int laneoff = (my * 128 + mx) * 2;
    const char* tb = (const char*)tab;
#pragma unroll
    for (int ni = 0; ni < 16; ni++) {
#pragma unroll
        for (int r = 0; r < 4; r++) {
            int n = ni * 16 + 4 * g + r;
            uint4 pw = prm[n];
            int va = (int)pw.z + laneoff;
            float a0 = bflo(*(const unsigned short*)(tb + va));
            float a1 = bflo(*(const unsigned short*)(tb + va + 2));
            float b0 = bflo(*(const unsigned short*)(tb + va + 256));
            float b1 = bflo(*(const unsigned short*)(tb + va + 258));
            float t = fmaf(bflo(pw.x), a0, acc[ni][r]);
            t = fmaf(bfhi(pw.x), a1, t);
            t = fmaf(bflo(pw.y), b0, t);
            t = fmaf(bfhi(pw.y), b1, t);
            acc[ni][r] = t;
        }
    }

    // ---- softmax over n (in-register + shfl_xor over g-groups) ----
    float mxv = -1e30f;
#pragma unroll
    for (int ni = 0; ni < 16; ni++)
        mxv = fmaxf(mxv, fmaxf(fmaxf(acc[ni][0], acc[ni][1]),
                               fmaxf(acc[ni][2], acc[ni][3])));
    mxv = fmaxf(mxv, __shfl_xor(mxv, 16));
    mxv = fmaxf(mxv, __shfl_xor(mxv, 32));
    float sum = 0.f;
    unsigned dwA[16], dwB[16];
#pragma unroll
    for (int ni = 0; ni < 16; ni++) {
        float e0 = __expf(acc[ni][0] - mxv);
        float e1 = __expf(acc[ni][1] - mxv);
        float e2 = __expf(acc[ni][2] - mxv);
        float e3 = __expf(acc[ni][3] - mxv);
        sum += (e0 + e1) + (e2 + e3);
        asm("v_cvt_pk_bf16_f32 %0, %1, %2" : "=v"(dwA[ni]) : "v"(e0), "v"(e1));
        asm("v_cvt_pk_bf16_f32 %0, %1, %2" : "=v"(dwB[ni]) : "v"(e2), "v"(e3));
    }
    sum += __shfl_xor(sum, 16);
    sum += __shfl_xor(sum, 32);

    // ---- PV: pf = P^T[32st+8g+j][lm] assembled via shfl exchange ----
    int src0 = ((g & 1) << 5) + lm;           // lane 16*(2*(g&1)) + lm
    int src1 = src0 + 16;
    bool sel = (g >> 1) != 0;
    const unsigned short* vb0 = vbf + ((long long)pb * 128 + h * 32 + lm) * 256
                                + 8 * g;
    f32x4 o0 = zero, o1 = zero;
#pragma unroll
    for (int st = 0; st < 8; st++) {
        unsigned d0a = __shfl(dwA[2 * st], src0), d0b = __shfl(dwA[2 * st + 1], src0);
        unsigned d1a = __shfl(dwB[2 * st], src0), d1b = __shfl(dwB[2 * st + 1], src0);
        unsigned d2a = __shfl(dwA[2 * st], src1), d2b = __shfl(dwA[2 * st + 1], src1);
        unsigned d3a = __shfl(dwB[2 * st], src1), d3b = __shfl(dwB[2 * st + 1], src1);
        union { unsigned u[4]; bf16x8 v; } pf;
        pf.u[0] = sel ? d0b : d0a;
        pf.u[1] = sel ? d1b : d1a;
        pf.u[2] = sel ? d2b : d2a;
        pf.u[3] = sel ? d3b : d3a;
        bf16x8 v0 = *(const bf16x8*)(vb0 + st * 32);
        bf16x8 v1 = *(const bf16x8*)(vb0 + 4096 + st * 32);
        o0 = __builtin_amdgcn_mfma_f32_16x16x32_bf16(v0, pf.v, o0, 0, 0, 0);
        o1 = __builtin_amdgcn_mfma_f32_16x16x32_bf16(v1, pf.v, o1, 0, 0, 0);
    }

    float inv = 1.f / sum;
    float* ob = obuf + ((long long)pb * 128 + h * 32) * HW + my * 64 + mx;
#pragma unroll
    for (int r = 0; r < 4; r++) {
        ob[(g * 4 + r) * HW] = o0[r] * inv;
        ob[(16 + g * 4 + r) * HW] = o1[r] * inv;
    }
}

// ---------------------------------------------------------------------------
// 7) attn_out = Wo @ o + bo, added into d_out channels 128:256.
//    vs=0 -> var1 (p=0); vs=1 -> var2 (p=1 AND p=2, K=256).
__global__ __launch_bounds__(128) void conv_wo(const float* __restrict__ obuf,
                                               const float* __restrict__ Wo,
                                               const float* __restrict__ bo,
                                               float* __restrict__ out) {
    int blk = blockIdx.x;               // 2*BB*128 = 1024
    int vs = blk >> 9;
    int r = blk & 511;
    int b = r >> 7;
    int tile = r & 127;
    int m0 = tile * 32;
    int np = vs + 1;
    __shared__ float4 xt4[256][8];
    for (int pi = 0; pi < np; pi++) {
        int p = vs ? (1 + pi) : 0;
        const float* X = obuf + ((long long)(p * 4 + b)) * 128 * HW;
        for (int idx = threadIdx.x; idx < 1024; idx += 128) {
            int cc = idx >> 3, i8 = idx & 7;
            xt4[pi * 128 + cc][i8] = *(const float4*)(X + (long long)cc * HW + m0 + i8 * 4);
        }
    }
    __syncthreads();
    int c = threadIdx.x;
    float4 a4[8];
#pragma unroll
    for (int i = 0; i < 8; i++) a4[i] = make_float4(0.f, 0.f, 0.f, 0.f);
    float bias = 0.f;
    for (int pi = 0; pi < np; pi++) {
        int p = vs ? (1 + pi) : 0;
        bias += bo[p * 128 + c];
        const float4* Wrow = (const float4*)(Wo + (p * 128 + c) * 128);
        for (int cp4 = 0; cp4 < 32; cp4++) {
            float4 w = Wrow[cp4];
#pragma unroll
            for (int k = 0; k < 4; k++) {
                float wv = (k == 0) ? w.x : (k == 1) ? w.y : (k == 2) ? w.z : w.w;
#pragma unroll
                for (int i = 0; i < 8; i++) {
                    float4 xv = xt4[pi * 128 + cp4 * 4 + k][i];
                    a4[i].x += wv * xv.x; a4[i].y += wv * xv.y;
                    a4[i].z += wv * xv.z; a4[i].w += wv * xv.w;
                }
            }
        }
    }
    int qi = vs + 1;
    float4* Y = (float4*)(out + (((long long)(qi * 4 + b)) * CC + 128 + c) * HW + m0);
#pragma unroll
    for (int i = 0; i < 8; i++) {
        float4 y = Y[i];
        y.x += a4[i].x + bias; y.y += a4[i].y + bias;
        y.z += a4[i].z + bias; y.w += a4[i].w + bias;
        Y[i] = y;
    }
}

// ---------------------------------------------------------------------------
extern "C" void kernel_launch(void* const* d_in, const int* in_sizes, int n_in,
                              void* d_out, int out_size, void* d_ws, size_t ws_size,
                              hipStream_t stream) {
    const float* x0 = (const float*)d_in[0];
    const float* x1 = (const float*)d_in[1];
    const float* x2 = (const float*)d_in[2];
    const float* Wq = (const float*)d_in[3];
    const float* bq = (const float*)d_in[4];
    const float* Wk = (const float*)d_in[5];
    const float* bk = (const float*)d_in[6];
    const float* Wv = (const float*)d_in[7];
    const float* bv = (const float*)d_in[8];
    const float* Wo = (const float*)d_in[9];
    const float* bo = (const float*)d_in[10];
    const float* dw_w = (const float*)d_in[11];
    const float* dw_b = (const float*)d_in[12];
    const float* ln_g = (const float*)d_in[13];
    const float* ln_b = (const float*)d_in[14];
    const float* pw_w = (const float*)d_in[15];
    const float* rpe = (const float*)d_in[16];
    float* out = (float*)d_out;

    // workspace layout (float units). obuf aliases qbuf: qbuf (f32) is dead
    // after offset_net, before attn writes obuf.
    float* ws = (float*)d_ws;
    float* qbuf = ws;                                   // 6291456 f
    float* obuf = qbuf;                                 // alias (disjoint lifetime)
    float* posb = ws + 6291456;                         // 6144 f
    float* xsb  = posb + 6144;                          // 393216 f
    unsigned short* qbf = (unsigned short*)(xsb + 393216);   // 12582912 s
    unsigned short* kbf = qbf + 12582912;                    // 393216 s
    unsigned short* vbf = kbf + 393216;                      // 393216 s
    unsigned short* tabbf = vbf + 393216;                    // 196608 s
    uint4* prmb = (uint4*)(tabbf + 196608);                  // 3072 uint4
    // total ~ 54 MB

    copy_init<<<2048, 256, 0, stream>>>(x0, x1, x2, out);
    prep_table<<<12, 256, 0, stream>>>(rpe, tabbf);
    conv_q<<<NP * BB * 128, 128, 0, stream>>>(x1, x2, Wq, bq, qbuf, qbf);
    offset_net<<<NP * BB * 256, 128, 0, stream>>>(qbuf, dw_w, dw_b, ln_g, ln_b,
                                                  pw_w, posb);
    prep_params<<<12, 256, 0, stream>>>(posb, prmb);
    sample_xs<<<NP * BB * 256, 128, 0, stream>>>(x0, x1, posb, xsb);
    conv_kv<<<NP * BB * 8, 256, 0, stream>>>(xsb, Wk, bk, Wv, bv, kbf, vbf);
    attn_mfma<<<NP * BB * HEADS * 64, 256, 0, stream>>>(qbf, kbf, vbf, tabbf,
                                                        prmb, obuf);
    conv_wo<<<2 * BB * 128, 128, 0, stream>>>(obuf, Wo, bo, out);
}